// Round 1
// baseline (678.735 us; speedup 1.0000x reference)
//
#include <hip/hip_runtime.h>
#include <hip/hip_bf16.h>

typedef unsigned long long u64;
typedef __bf16 bf16x8 __attribute__((ext_vector_type(8)));
typedef float f32x4 __attribute__((ext_vector_type(4)));
typedef unsigned short ushort8_t __attribute__((ext_vector_type(8)));

#define TOKS 8192
#define DMODEL 2048
#define FD 1024
#define NEXP 7
#define CAP 1170
#define CAPP 1280

__device__ __forceinline__ unsigned short f2bf(float f) {
  __hip_bfloat16 b = __float2bfloat16(f);
  return __builtin_bit_cast(unsigned short, b);
}
__device__ __forceinline__ float bf2f(unsigned short u) {
  __hip_bfloat16 b = __builtin_bit_cast(__hip_bfloat16, u);
  return __bfloat162float(b);
}
__device__ __forceinline__ void gload_lds16(const void* g, void* l) {
  __builtin_amdgcn_global_load_lds(
      (const __attribute__((address_space(1))) void*)g,
      (__attribute__((address_space(3))) void*)l, 16, 0, 0);
}

// ---------------- x fp32 -> bf16 ----------------
__global__ void k_convert_x(const float* __restrict__ x,
                            unsigned short* __restrict__ xb, long n4) {
  long i = (long)blockIdx.x * blockDim.x + threadIdx.x;
  long stride = (long)gridDim.x * blockDim.x;
  for (; i < n4; i += stride) {
    float4 v = ((const float4*)x)[i];
    ushort4 o;
    o.x = f2bf(v.x); o.y = f2bf(v.y); o.z = f2bf(v.z); o.w = f2bf(v.w);
    ((ushort4*)xb)[i] = o;
  }
}

// ---------------- transpose fp32 [R][C] -> bf16 [C][R], batched z (0=shared,1..7=routed) ----------------
__global__ void k_transpose_bf16(const float* __restrict__ in0,
                                 const float* __restrict__ inr,
                                 unsigned short* __restrict__ out,
                                 int R, int C) {
  __shared__ float tile[32][33];
  int z = blockIdx.z;
  const float* in = (z == 0) ? in0 : (inr + (long)(z - 1) * R * C);
  unsigned short* o = out + (long)z * R * C;
  int c0 = blockIdx.x * 32;
  int r0 = blockIdx.y * 32;
  int tx = threadIdx.x, ty = threadIdx.y; // (32,8)
#pragma unroll
  for (int k = 0; k < 4; ++k)
    tile[ty + 8 * k][tx] = in[(long)(r0 + ty + 8 * k) * C + c0 + tx];
  __syncthreads();
#pragma unroll
  for (int k = 0; k < 4; ++k)
    o[(long)(c0 + ty + 8 * k) * R + r0 + tx] = f2bf(tile[tx][ty + 8 * k]);
}

// ---------------- gating: fp64 dot, sigmoid, top-2, emit sort keys ----------------
__global__ void k_gating(const float* __restrict__ x,
                         const float* __restrict__ gw,   // [DMODEL][NEXP]
                         const float* __restrict__ bias, // [NEXP]
                         u64* __restrict__ keys) {       // [NEXP][TOKS]
  int wave = threadIdx.x >> 6;
  int lane = threadIdx.x & 63;
  int t = blockIdx.x * 4 + wave;
  const float* xr = x + (long)t * DMODEL;
  double acc[NEXP];
#pragma unroll
  for (int e = 0; e < NEXP; ++e) acc[e] = 0.0;
  for (int i = lane; i < DMODEL; i += 64) {
    double xv = (double)xr[i];
    const float* g = gw + (long)i * NEXP;
#pragma unroll
    for (int e = 0; e < NEXP; ++e) acc[e] += xv * (double)g[e];
  }
#pragma unroll
  for (int e = 0; e < NEXP; ++e) {
    for (int off = 32; off > 0; off >>= 1)
      acc[e] += __shfl_down(acc[e], off, 64);
  }
  if (lane == 0) {
    float aff[NEXP];
#pragma unroll
    for (int e = 0; e < NEXP; ++e) {
      double lg = acc[e] + (double)bias[e];
      aff[e] = (float)(1.0 / (1.0 + exp(-lg)));
    }
    int i1 = 0;
    for (int e = 1; e < NEXP; ++e) if (aff[e] > aff[i1]) i1 = e;
    int i2 = -1;
    for (int e = 0; e < NEXP; ++e) {
      if (e == i1) continue;
      if (i2 < 0 || aff[e] > aff[i2]) i2 = e;
    }
#pragma unroll
    for (int e = 0; e < NEXP; ++e) {
      u64 key = (u64)(0xFFFFFFFFu - (unsigned)t);
      if (e == i1 || e == i2) key |= ((u64)__float_as_uint(aff[e])) << 32;
      keys[(long)e * TOKS + t] = key;
    }
  }
}

// ---------------- per-expert bitonic sort (desc) + capacity selection ----------------
__global__ __launch_bounds__(1024) void k_sort_select(
    const u64* __restrict__ keys, int* __restrict__ sel,
    float* __restrict__ selw) {
  __shared__ u64 s[TOKS];
  int e = blockIdx.x;
  int tid = threadIdx.x;
  for (int i = tid; i < TOKS; i += 1024) s[i] = keys[(long)e * TOKS + i];
  __syncthreads();
  for (int k = 2; k <= TOKS; k <<= 1) {
    for (int j = k >> 1; j > 0; j >>= 1) {
      for (int ii = tid; ii < TOKS; ii += 1024) {
        int ixj = ii ^ j;
        if (ixj > ii) {
          u64 a = s[ii], b = s[ixj];
          bool descRegion = ((ii & k) == 0);
          bool doSwap = descRegion ? (a < b) : (a > b);
          if (doSwap) { s[ii] = b; s[ixj] = a; }
        }
      }
      __syncthreads();
    }
  }
  for (int i = tid; i < CAPP; i += 1024) {
    u64 key = s[i];
    unsigned vb = (unsigned)(key >> 32);
    int tok = (int)(0xFFFFFFFFu - (unsigned)(key & 0xFFFFFFFFull));
    float w = (i < CAP && vb != 0u) ? __uint_as_float(vb) : 0.0f;
    sel[e * CAPP + i] = tok;
    selw[e * CAPP + i] = w;
  }
}

// ---------------- SwiGLU activation: h[rows][2F] -> a[rows][F] ----------------
__global__ void k_act(const unsigned short* __restrict__ h,
                      unsigned short* __restrict__ a, int rows, int F) {
  int fw = F / 8;
  long total = (long)rows * fw;
  long idx = (long)blockIdx.x * blockDim.x + threadIdx.x;
  long stride = (long)gridDim.x * blockDim.x;
  for (; idx < total; idx += stride) {
    long t = idx / fw;
    int f = (int)(idx % fw) * 8;
    const unsigned short* hr = h + t * (2L * F);
    ushort8_t x1 = *(const ushort8_t*)&hr[f];
    ushort8_t x2 = *(const ushort8_t*)&hr[F + f];
    ushort8_t o;
#pragma unroll
    for (int j = 0; j < 8; ++j) {
      float v1 = bf2f(x1[j]);
      float v2 = bf2f(x2[j]);
      float s = v2 / (1.0f + __expf(-v2));
      o[j] = f2bf(v1 * s);
    }
    *(ushort8_t*)&a[t * F + f] = o;
  }
}

// ---------------- GEMM: C[M,N] = A[M,K] * B[N,K]^T (bf16 in, fp32 acc) ----------------
// EPI: 0 -> store bf16 C (+z*strideC); 1 -> store fp32 Cf32; 2 -> weighted atomicAdd scatter to Cf32
// GATHER: A row indices come from sel[z*CAPP + row]
template <int EPI, bool GATHER>
__global__ __launch_bounds__(256) void k_gemm_bt(
    const unsigned short* __restrict__ Abase,
    const unsigned short* __restrict__ Bbase,
    unsigned short* __restrict__ Cbf, float* __restrict__ Cf32,
    const int* __restrict__ sel, const float* __restrict__ selw, int N, int K,
    long strideA, long strideB, long strideC) {
  __shared__ unsigned short ldsA[128 * 32];
  __shared__ unsigned short ldsB[128 * 32];
  const int tid = threadIdx.x;
  const int wid = tid >> 6;
  const int lane = tid & 63;
  const int z = blockIdx.z;
  const long m0 = (long)blockIdx.y * 128;
  const long n0 = (long)blockIdx.x * 128;

  const unsigned short* A = Abase + (GATHER ? 0L : (long)z * strideA);
  const unsigned short* B = Bbase + (long)z * strideB;

  const int wm = (wid >> 1) * 64;
  const int wn = (wid & 1) * 64;
  const int kq = lane >> 4;
  const int lr = lane & 15;

  f32x4 acc[4][4] = {};

  const int chunk = wid * 2;
  const int srow0 = chunk * 16 + (lane >> 2);
  const int srow1 = srow0 + 16;
  const int scol = (lane & 3) * 8;

  long arow0, arow1;
  if (GATHER) {
    arow0 = sel[z * CAPP + (int)m0 + srow0];
    arow1 = sel[z * CAPP + (int)m0 + srow1];
  } else {
    arow0 = m0 + srow0;
    arow1 = m0 + srow1;
  }
  const long brow0 = n0 + srow0;
  const long brow1 = n0 + srow1;

  const unsigned short* a0p = A + arow0 * K + scol;
  const unsigned short* a1p = A + arow1 * K + scol;
  const unsigned short* b0p = B + brow0 * K + scol;
  const unsigned short* b1p = B + brow1 * K + scol;

  for (int kk = 0; kk < K; kk += 32) {
    gload_lds16(a0p + kk, (void*)&ldsA[(chunk + 0) * 512]);
    gload_lds16(a1p + kk, (void*)&ldsA[(chunk + 1) * 512]);
    gload_lds16(b0p + kk, (void*)&ldsB[(chunk + 0) * 512]);
    gload_lds16(b1p + kk, (void*)&ldsB[(chunk + 1) * 512]);
    __syncthreads();
    bf16x8 af[4], bfr[4];
#pragma unroll
    for (int m = 0; m < 4; ++m)
      af[m] = *(const bf16x8*)&ldsA[(wm + m * 16 + lr) * 32 + kq * 8];
#pragma unroll
    for (int n = 0; n < 4; ++n)
      bfr[n] = *(const bf16x8*)&ldsB[(wn + n * 16 + lr) * 32 + kq * 8];
#pragma unroll
    for (int m = 0; m < 4; ++m)
#pragma unroll
      for (int n = 0; n < 4; ++n)
        acc[m][n] =
            __builtin_amdgcn_mfma_f32_16x16x32_bf16(af[m], bfr[n], acc[m][n], 0, 0, 0);
    __syncthreads();
  }

  const int r0 = (lane >> 4) * 4;
  const int cc = lane & 15;

  if (EPI == 0) {
    unsigned short* C = Cbf + (long)z * strideC;
#pragma unroll
    for (int m = 0; m < 4; ++m)
#pragma unroll
      for (int r = 0; r < 4; ++r) {
        long row = m0 + wm + m * 16 + r0 + r;
#pragma unroll
        for (int n = 0; n < 4; ++n) {
          long col = n0 + wn + n * 16 + cc;
          C[row * N + col] = f2bf(acc[m][n][r]);
        }
      }
  } else if (EPI == 1) {
#pragma unroll
    for (int m = 0; m < 4; ++m)
#pragma unroll
      for (int r = 0; r < 4; ++r) {
        long row = m0 + wm + m * 16 + r0 + r;
#pragma unroll
        for (int n = 0; n < 4; ++n)
          Cf32[row * N + n0 + wn + n * 16 + cc] = acc[m][n][r];
      }
  } else {
#pragma unroll
    for (int m = 0; m < 4; ++m)
#pragma unroll
      for (int r = 0; r < 4; ++r) {
        int row = (int)m0 + wm + m * 16 + r0 + r;
        int tok = sel[z * CAPP + row];
        float w = selw[z * CAPP + row];
        if (w != 0.0f) {
#pragma unroll
          for (int n = 0; n < 4; ++n)
            atomicAdd(&Cf32[(long)tok * N + n0 + wn + n * 16 + cc],
                      acc[m][n][r] * w);
        }
      }
  }
}

extern "C" void kernel_launch(void* const* d_in, const int* in_sizes, int n_in,
                              void* d_out, int out_size, void* d_ws,
                              size_t ws_size, hipStream_t stream) {
  (void)in_sizes; (void)n_in; (void)out_size; (void)ws_size;
  const float* x = (const float*)d_in[0];
  const float* gw = (const float*)d_in[1];
  const float* eb = (const float*)d_in[2];
  const float* sw1 = (const float*)d_in[3];
  const float* sw2 = (const float*)d_in[4];
  const float* rw1 = (const float*)d_in[5];
  const float* rw2 = (const float*)d_in[6];
  float* out = (float*)d_out;

  char* ws = (char*)d_ws;
  size_t off = 0;
  auto alloc = [&](size_t bytes) {
    size_t o = off;
    off += (bytes + 255) & ~(size_t)255;
    return o;
  };
  unsigned short* xb   = (unsigned short*)(ws + alloc((size_t)TOKS * DMODEL * 2));
  unsigned short* w1t  = (unsigned short*)(ws + alloc((size_t)8 * DMODEL * (2 * FD) * 2));
  unsigned short* w2t  = (unsigned short*)(ws + alloc((size_t)8 * DMODEL * FD * 2));
  unsigned short* h_sh = (unsigned short*)(ws + alloc((size_t)TOKS * (2 * FD) * 2));
  unsigned short* a_sh = (unsigned short*)(ws + alloc((size_t)TOKS * FD * 2));
  unsigned short* h_r  = (unsigned short*)(ws + alloc((size_t)NEXP * CAPP * (2 * FD) * 2));
  unsigned short* a_r  = (unsigned short*)(ws + alloc((size_t)NEXP * CAPP * FD * 2));
  u64* keys            = (u64*)(ws + alloc((size_t)NEXP * TOKS * 8));
  int* sel             = (int*)(ws + alloc((size_t)NEXP * CAPP * 4));
  float* selw          = (float*)(ws + alloc((size_t)NEXP * CAPP * 4));

  // 1. x -> bf16
  k_convert_x<<<8192, 256, 0, stream>>>(x, xb, (long)TOKS * DMODEL / 4);
  // 2./3. weight transposes (w1: [2048][2048]->[2048][2048]; w2: [1024][2048]->[2048][1024])
  dim3 tb(32, 8);
  k_transpose_bf16<<<dim3(64, 64, 8), tb, 0, stream>>>(sw1, rw1, w1t, DMODEL, 2 * FD);
  k_transpose_bf16<<<dim3(64, 32, 8), tb, 0, stream>>>(sw2, rw2, w2t, FD, DMODEL);
  // 4. gating
  k_gating<<<TOKS / 4, 256, 0, stream>>>(x, gw, eb, keys);
  // 5. per-expert selection
  k_sort_select<<<NEXP, 1024, 0, stream>>>(keys, sel, selw);
  // 6. shared GEMM1: xb[8192,2048] @ w1t[z=0][2048,2048]^T -> h_sh bf16
  k_gemm_bt<0, false><<<dim3(16, 64, 1), 256, 0, stream>>>(
      xb, w1t, h_sh, nullptr, nullptr, nullptr, 2 * FD, DMODEL, 0, 0, 0);
  // 7. shared activation
  k_act<<<2048, 256, 0, stream>>>(h_sh, a_sh, TOKS, FD);
  // 8. shared GEMM2 -> d_out fp32 (full overwrite)
  k_gemm_bt<1, false><<<dim3(16, 64, 1), 256, 0, stream>>>(
      a_sh, w2t, nullptr, out, nullptr, nullptr, DMODEL, FD, 0, 0, 0);
  // 9. routed GEMM1 (gathered A): z=expert
  k_gemm_bt<0, true><<<dim3(16, CAPP / 128, NEXP), 256, 0, stream>>>(
      xb, w1t + (size_t)DMODEL * (2 * FD), h_r, nullptr, sel, nullptr, 2 * FD,
      DMODEL, 0, (long)DMODEL * (2 * FD), (long)CAPP * (2 * FD));
  // 10. routed activation (treat as [7*1280][2048] -> [7*1280][1024])
  k_act<<<2048, 256, 0, stream>>>(h_r, a_r, NEXP * CAPP, FD);
  // 11. routed GEMM2 with weighted atomic scatter into d_out
  k_gemm_bt<2, false><<<dim3(16, CAPP / 128, NEXP), 256, 0, stream>>>(
      a_r, w2t + (size_t)DMODEL * FD, nullptr, out, sel, selw, DMODEL, FD,
      (long)CAPP * FD, (long)DMODEL * FD, 0);
}

// Round 2
// 631.402 us; speedup vs baseline: 1.0750x; 1.0750x over previous
//
#include <hip/hip_runtime.h>
#include <hip/hip_bf16.h>

typedef unsigned long long u64;
typedef __bf16 bf16x8 __attribute__((ext_vector_type(8)));
typedef float f32x4 __attribute__((ext_vector_type(4)));
typedef unsigned short ushort8_t __attribute__((ext_vector_type(8)));

#define TOKS 8192
#define DMODEL 2048
#define FD 1024
#define NEXP 7
#define CAP 1170
#define CAPP 1280

__device__ __forceinline__ unsigned short f2bf(float f) {
  __hip_bfloat16 b = __float2bfloat16(f);
  return __builtin_bit_cast(unsigned short, b);
}
__device__ __forceinline__ float bf2f(unsigned short u) {
  __hip_bfloat16 b = __builtin_bit_cast(__hip_bfloat16, u);
  return __bfloat162float(b);
}
__device__ __forceinline__ void gload_lds16(const void* g, void* l) {
  __builtin_amdgcn_global_load_lds(
      (const __attribute__((address_space(1))) void*)g,
      (__attribute__((address_space(3))) void*)l, 16, 0, 0);
}

// ---------------- x fp32 -> bf16 ----------------
__global__ void k_convert_x(const float* __restrict__ x,
                            unsigned short* __restrict__ xb, long n4) {
  long i = (long)blockIdx.x * blockDim.x + threadIdx.x;
  long stride = (long)gridDim.x * blockDim.x;
  for (; i < n4; i += stride) {
    float4 v = ((const float4*)x)[i];
    ushort4 o;
    o.x = f2bf(v.x); o.y = f2bf(v.y); o.z = f2bf(v.z); o.w = f2bf(v.w);
    ((ushort4*)xb)[i] = o;
  }
}

// ---------------- transpose fp32 [R][C] -> bf16 [C][R], batched z (0=shared,1..7=routed) ----------------
__global__ void k_transpose_bf16(const float* __restrict__ in0,
                                 const float* __restrict__ inr,
                                 unsigned short* __restrict__ out,
                                 int R, int C) {
  __shared__ float tile[32][33];
  int z = blockIdx.z;
  const float* in = (z == 0) ? in0 : (inr + (long)(z - 1) * R * C);
  unsigned short* o = out + (long)z * R * C;
  int c0 = blockIdx.x * 32;
  int r0 = blockIdx.y * 32;
  int tx = threadIdx.x, ty = threadIdx.y; // (32,8)
#pragma unroll
  for (int k = 0; k < 4; ++k)
    tile[ty + 8 * k][tx] = in[(long)(r0 + ty + 8 * k) * C + c0 + tx];
  __syncthreads();
#pragma unroll
  for (int k = 0; k < 4; ++k)
    o[(long)(c0 + ty + 8 * k) * R + r0 + tx] = f2bf(tile[tx][ty + 8 * k]);
}

// ---------------- gating: fp64 dot, sigmoid, top-2, emit sort keys ----------------
__global__ void k_gating(const float* __restrict__ x,
                         const float* __restrict__ gw,   // [DMODEL][NEXP]
                         const float* __restrict__ bias, // [NEXP]
                         u64* __restrict__ keys) {       // [NEXP][TOKS]
  int wave = threadIdx.x >> 6;
  int lane = threadIdx.x & 63;
  int t = blockIdx.x * 4 + wave;
  const float* xr = x + (long)t * DMODEL;
  double acc[NEXP];
#pragma unroll
  for (int e = 0; e < NEXP; ++e) acc[e] = 0.0;
  for (int i = lane; i < DMODEL; i += 64) {
    double xv = (double)xr[i];
    const float* g = gw + (long)i * NEXP;
#pragma unroll
    for (int e = 0; e < NEXP; ++e) acc[e] += xv * (double)g[e];
  }
#pragma unroll
  for (int e = 0; e < NEXP; ++e) {
    for (int off = 32; off > 0; off >>= 1)
      acc[e] += __shfl_down(acc[e], off, 64);
  }
  if (lane == 0) {
    float aff[NEXP];
#pragma unroll
    for (int e = 0; e < NEXP; ++e) {
      double lg = acc[e] + (double)bias[e];
      aff[e] = (float)(1.0 / (1.0 + exp(-lg)));
    }
    int i1 = 0;
    for (int e = 1; e < NEXP; ++e) if (aff[e] > aff[i1]) i1 = e;
    int i2 = -1;
    for (int e = 0; e < NEXP; ++e) {
      if (e == i1) continue;
      if (i2 < 0 || aff[e] > aff[i2]) i2 = e;
    }
#pragma unroll
    for (int e = 0; e < NEXP; ++e) {
      u64 key = (u64)(0xFFFFFFFFu - (unsigned)t);
      if (e == i1 || e == i2) key |= ((u64)__float_as_uint(aff[e])) << 32;
      keys[(long)e * TOKS + t] = key;
    }
  }
}

// ---------------- per-expert bitonic sort (desc) + capacity selection ----------------
__global__ __launch_bounds__(1024) void k_sort_select(
    const u64* __restrict__ keys, int* __restrict__ sel,
    float* __restrict__ selw) {
  __shared__ u64 s[TOKS];
  int e = blockIdx.x;
  int tid = threadIdx.x;
  for (int i = tid; i < TOKS; i += 1024) s[i] = keys[(long)e * TOKS + i];
  __syncthreads();
  for (int k = 2; k <= TOKS; k <<= 1) {
    for (int j = k >> 1; j > 0; j >>= 1) {
      for (int ii = tid; ii < TOKS; ii += 1024) {
        int ixj = ii ^ j;
        if (ixj > ii) {
          u64 a = s[ii], b = s[ixj];
          bool descRegion = ((ii & k) == 0);
          bool doSwap = descRegion ? (a < b) : (a > b);
          if (doSwap) { s[ii] = b; s[ixj] = a; }
        }
      }
      __syncthreads();
    }
  }
  for (int i = tid; i < CAPP; i += 1024) {
    u64 key = s[i];
    unsigned vb = (unsigned)(key >> 32);
    int tok = (int)(0xFFFFFFFFu - (unsigned)(key & 0xFFFFFFFFull));
    float w = (i < CAP && vb != 0u) ? __uint_as_float(vb) : 0.0f;
    sel[e * CAPP + i] = tok;
    selw[e * CAPP + i] = w;
  }
}

// ---------------- SwiGLU activation: h[rows][2F] -> a[rows][F] ----------------
__global__ void k_act(const unsigned short* __restrict__ h,
                      unsigned short* __restrict__ a, int rows, int F) {
  int fw = F / 8;
  long total = (long)rows * fw;
  long idx = (long)blockIdx.x * blockDim.x + threadIdx.x;
  long stride = (long)gridDim.x * blockDim.x;
  for (; idx < total; idx += stride) {
    long t = idx / fw;
    int f = (int)(idx % fw) * 8;
    const unsigned short* hr = h + t * (2L * F);
    ushort8_t x1 = *(const ushort8_t*)&hr[f];
    ushort8_t x2 = *(const ushort8_t*)&hr[F + f];
    ushort8_t o;
#pragma unroll
    for (int j = 0; j < 8; ++j) {
      float v1 = bf2f(x1[j]);
      float v2 = bf2f(x2[j]);
      float s = v2 / (1.0f + __expf(-v2));
      o[j] = f2bf(v1 * s);
    }
    *(ushort8_t*)&a[t * F + f] = o;
  }
}

// ---------------- 256x256 deep-pipelined GEMM: C[M,N] = A[M,K] * B[N,K]^T ----------------
// 512 threads = 8 waves (2 M x 4 N), per-wave 128x64 output, BK=32.
// 4 LDS buffers (128 KiB dynamic), 3-tile prefetch, counted vmcnt(8), 1 barrier/K-step.
// T2 XOR swizzle (both sides), T5 setprio around MFMA cluster, T1 XCD block swizzle.
// EPI: 0 -> bf16 C (+z*strideC); 1 -> fp32 C; 2 -> weighted atomicAdd scatter via sel/selw.
template <int EPI, bool GATHER>
__global__ __launch_bounds__(512, 2) void k_gemm256(
    const unsigned short* __restrict__ Abase,
    const unsigned short* __restrict__ Bbase,
    unsigned short* __restrict__ Cbf, float* __restrict__ Cf32,
    const int* __restrict__ sel, const float* __restrict__ selw, int N, int K,
    long strideA, long strideB, long strideC) {
  extern __shared__ unsigned short lds[];  // 4 * (A 8192 + B 8192) shorts = 128 KiB

  const int tid = threadIdx.x;
  const int wid = tid >> 6;
  const int lane = tid & 63;

  // XCD-aware block swizzle (all grids are multiples of 8)
  long lin = blockIdx.x + (long)gridDim.x * (blockIdx.y + (long)gridDim.y * blockIdx.z);
  long nwg = (long)gridDim.x * gridDim.y * gridDim.z;
  long swz = (lin & 7) * (nwg >> 3) + (lin >> 3);
  int bx = (int)(swz % gridDim.x);
  long rem = swz / gridDim.x;
  int by = (int)(rem % gridDim.y);
  int z = (int)(rem / gridDim.y);

  const long m0 = (long)by * 256;
  const long n0 = (long)bx * 256;

  const unsigned short* A = Abase + (GATHER ? 0L : (long)z * strideA);
  const unsigned short* Bm = Bbase + (long)z * strideB;

  const int wr = wid >> 2;  // 0..1
  const int wc = wid & 3;   // 0..3

  // ---- staging source addresses (pre-swizzled global columns; LDS dest linear) ----
  const int r_local = lane >> 2;
  const int csw = ((lane & 3) ^ ((lane >> 3) & 3)) * 8;  // swizzled col group
  const unsigned short* aSrc[2];
  const unsigned short* bSrc[2];
#pragma unroll
  for (int a = 0; a < 2; ++a) {
    int tr = wid * 32 + a * 16 + r_local;
    long grow = GATHER ? (long)sel[z * CAPP + (int)m0 + tr] : (m0 + tr);
    aSrc[a] = A + grow * K + csw;
    bSrc[a] = Bm + (n0 + tr) * K + csw;
  }
  const int ldsA_dst = wid * 1024;         // shorts, wave-uniform; + a*512
  const int ldsB_dst = 8192 + wid * 1024;  // shorts

  // ---- LDS read offsets (swizzled) ----
  const int lr = lane & 15, kq = lane >> 4;
  const int slot = kq ^ ((lr >> 1) & 3);
  const int aoff = (wr * 128 + lr) * 32 + slot * 8;        // + m*512 shorts
  const int boff = 8192 + (wc * 64 + lr) * 32 + slot * 8;  // + n*512 shorts

  const int nk = K >> 5;

  auto STAGE = [&](int ts, int buf) {
    const long ko = (long)ts << 5;
    unsigned short* lb = lds + buf * 16384;
#pragma unroll
    for (int a = 0; a < 2; ++a) {
      gload_lds16(aSrc[a] + ko, lb + ldsA_dst + a * 512);
      gload_lds16(bSrc[a] + ko, lb + ldsB_dst + a * 512);
    }
  };

  STAGE(0, 0);
  STAGE(1, 1);
  STAGE(2, 2);

  f32x4 acc[8][4] = {};

#pragma unroll 1
  for (int t = 0; t < nk; ++t) {
    // tile t's 4 loads are the oldest of 12 outstanding -> retire them; keep 8 in flight.
    // lgkmcnt(0): my previous-iteration ds_reads retired before anyone can restage that buffer.
    asm volatile("s_waitcnt vmcnt(8) lgkmcnt(0)" ::: "memory");
    __builtin_amdgcn_sched_barrier(0);
    __builtin_amdgcn_s_barrier();
    __builtin_amdgcn_sched_barrier(0);
    int ts = t + 3;
    if (ts >= nk) ts -= nk;       // tail: harmless dummy reload into a dead buffer
    STAGE(ts, (t + 3) & 3);
    const unsigned short* bufp = lds + (t & 3) * 16384;
    bf16x8 af[8], bfr[4];
#pragma unroll
    for (int m = 0; m < 8; ++m) af[m] = *(const bf16x8*)&bufp[aoff + m * 512];
#pragma unroll
    for (int n = 0; n < 4; ++n) bfr[n] = *(const bf16x8*)&bufp[boff + n * 512];
    __builtin_amdgcn_s_setprio(1);
#pragma unroll
    for (int m = 0; m < 8; ++m)
#pragma unroll
      for (int n = 0; n < 4; ++n)
        acc[m][n] = __builtin_amdgcn_mfma_f32_16x16x32_bf16(af[m], bfr[n],
                                                            acc[m][n], 0, 0, 0);
    __builtin_amdgcn_s_setprio(0);
  }

  const int r0q = (lane >> 4) * 4;
  const int cc = lane & 15;
  const long crow0 = m0 + wr * 128;
  const long ccol0 = n0 + wc * 64;

  if (EPI == 0) {
    unsigned short* C = Cbf + (long)z * strideC;
#pragma unroll
    for (int m = 0; m < 8; ++m)
#pragma unroll
      for (int r = 0; r < 4; ++r) {
        long row = crow0 + m * 16 + r0q + r;
#pragma unroll
        for (int n = 0; n < 4; ++n)
          C[row * N + ccol0 + n * 16 + cc] = f2bf(acc[m][n][r]);
      }
  } else if (EPI == 1) {
#pragma unroll
    for (int m = 0; m < 8; ++m)
#pragma unroll
      for (int r = 0; r < 4; ++r) {
        long row = crow0 + m * 16 + r0q + r;
#pragma unroll
        for (int n = 0; n < 4; ++n)
          Cf32[row * N + ccol0 + n * 16 + cc] = acc[m][n][r];
      }
  } else {
#pragma unroll
    for (int m = 0; m < 8; ++m)
#pragma unroll
      for (int r = 0; r < 4; ++r) {
        int srow = (int)crow0 + m * 16 + r0q + r;
        int tok = sel[z * CAPP + srow];
        float w = selw[z * CAPP + srow];
        if (w != 0.0f) {
#pragma unroll
          for (int n = 0; n < 4; ++n)
            atomicAdd(&Cf32[(long)tok * N + ccol0 + n * 16 + cc],
                      acc[m][n][r] * w);
        }
      }
  }
}

extern "C" void kernel_launch(void* const* d_in, const int* in_sizes, int n_in,
                              void* d_out, int out_size, void* d_ws,
                              size_t ws_size, hipStream_t stream) {
  (void)in_sizes; (void)n_in; (void)out_size; (void)ws_size;
  const float* x = (const float*)d_in[0];
  const float* gw = (const float*)d_in[1];
  const float* eb = (const float*)d_in[2];
  const float* sw1 = (const float*)d_in[3];
  const float* sw2 = (const float*)d_in[4];
  const float* rw1 = (const float*)d_in[5];
  const float* rw2 = (const float*)d_in[6];
  float* out = (float*)d_out;

  char* ws = (char*)d_ws;
  size_t off = 0;
  auto alloc = [&](size_t bytes) {
    size_t o = off;
    off += (bytes + 255) & ~(size_t)255;
    return o;
  };
  unsigned short* xb   = (unsigned short*)(ws + alloc((size_t)TOKS * DMODEL * 2));
  unsigned short* w1t  = (unsigned short*)(ws + alloc((size_t)8 * DMODEL * (2 * FD) * 2));
  unsigned short* w2t  = (unsigned short*)(ws + alloc((size_t)8 * DMODEL * FD * 2));
  unsigned short* h_sh = (unsigned short*)(ws + alloc((size_t)TOKS * (2 * FD) * 2));
  unsigned short* a_sh = (unsigned short*)(ws + alloc((size_t)TOKS * FD * 2));
  unsigned short* h_r  = (unsigned short*)(ws + alloc((size_t)NEXP * CAPP * (2 * FD) * 2));
  unsigned short* a_r  = (unsigned short*)(ws + alloc((size_t)NEXP * CAPP * FD * 2));
  u64* keys            = (u64*)(ws + alloc((size_t)NEXP * TOKS * 8));
  int* sel             = (int*)(ws + alloc((size_t)NEXP * CAPP * 4));
  float* selw          = (float*)(ws + alloc((size_t)NEXP * CAPP * 4));

  const size_t LDSB = 131072;  // 128 KiB dynamic LDS for k_gemm256

  // 1. x -> bf16
  k_convert_x<<<8192, 256, 0, stream>>>(x, xb, (long)TOKS * DMODEL / 4);
  // 2./3. weight transposes
  dim3 tb(32, 8);
  k_transpose_bf16<<<dim3(64, 64, 8), tb, 0, stream>>>(sw1, rw1, w1t, DMODEL, 2 * FD);
  k_transpose_bf16<<<dim3(64, 32, 8), tb, 0, stream>>>(sw2, rw2, w2t, FD, DMODEL);
  // 4. gating
  k_gating<<<TOKS / 4, 256, 0, stream>>>(x, gw, eb, keys);
  // 5. per-expert selection
  k_sort_select<<<NEXP, 1024, 0, stream>>>(keys, sel, selw);
  // 6. shared GEMM1: xb[8192,2048] @ w1t[z=0]^T -> h_sh bf16 [8192,2048]
  k_gemm256<0, false><<<dim3(8, 32, 1), 512, LDSB, stream>>>(
      xb, w1t, h_sh, nullptr, nullptr, nullptr, 2 * FD, DMODEL, 0, 0, 0);
  // 7. shared activation
  k_act<<<2048, 256, 0, stream>>>(h_sh, a_sh, TOKS, FD);
  // 8. shared GEMM2 -> d_out fp32 (full overwrite)
  k_gemm256<1, false><<<dim3(8, 32, 1), 512, LDSB, stream>>>(
      a_sh, w2t, nullptr, out, nullptr, nullptr, DMODEL, FD, 0, 0, 0);
  // 9. routed GEMM1 (gathered A): z=expert
  k_gemm256<0, true><<<dim3(8, CAPP / 256, NEXP), 512, LDSB, stream>>>(
      xb, w1t + (size_t)DMODEL * (2 * FD), h_r, nullptr, sel, nullptr, 2 * FD,
      DMODEL, 0, (long)DMODEL * (2 * FD), (long)CAPP * (2 * FD));
  // 10. routed activation
  k_act<<<2048, 256, 0, stream>>>(h_r, a_r, NEXP * CAPP, FD);
  // 11. routed GEMM2 with weighted atomic scatter into d_out
  k_gemm256<2, false><<<dim3(8, CAPP / 256, NEXP), 512, LDSB, stream>>>(
      a_r, w2t + (size_t)DMODEL * FD, nullptr, out, sel, selw, DMODEL, FD,
      (long)CAPP * FD, (long)DMODEL * FD, 0);
}

// Round 3
// 609.980 us; speedup vs baseline: 1.1127x; 1.0351x over previous
//
#include <hip/hip_runtime.h>
#include <hip/hip_bf16.h>

typedef unsigned long long u64;
typedef __bf16 bf16x8 __attribute__((ext_vector_type(8)));
typedef float f32x4 __attribute__((ext_vector_type(4)));
typedef unsigned short ushort8_t __attribute__((ext_vector_type(8)));

#define TOKS 8192
#define DMODEL 2048
#define FD 1024
#define NEXP 7
#define CAP 1170
#define CAPP 1280

#define MFMA16(a, b, c) __builtin_amdgcn_mfma_f32_16x16x32_bf16(a, b, c, 0, 0, 0)

__device__ __forceinline__ unsigned short f2bf(float f) {
  __hip_bfloat16 b = __float2bfloat16(f);
  return __builtin_bit_cast(unsigned short, b);
}
__device__ __forceinline__ float bf2f(unsigned short u) {
  __hip_bfloat16 b = __builtin_bit_cast(__hip_bfloat16, u);
  return __bfloat162float(b);
}
__device__ __forceinline__ void gload_lds16(const void* g, void* l) {
  __builtin_amdgcn_global_load_lds(
      (const __attribute__((address_space(1))) void*)g,
      (__attribute__((address_space(3))) void*)l, 16, 0, 0);
}

// ---------------- x fp32 -> bf16 ----------------
__global__ void k_convert_x(const float* __restrict__ x,
                            unsigned short* __restrict__ xb, long n4) {
  long i = (long)blockIdx.x * blockDim.x + threadIdx.x;
  long stride = (long)gridDim.x * blockDim.x;
  for (; i < n4; i += stride) {
    float4 v = ((const float4*)x)[i];
    ushort4 o;
    o.x = f2bf(v.x); o.y = f2bf(v.y); o.z = f2bf(v.z); o.w = f2bf(v.w);
    ((ushort4*)xb)[i] = o;
  }
}

// ---------------- transpose fp32 [R][C] -> bf16 [C][R], batched z ----------------
__global__ void k_transpose_bf16(const float* __restrict__ in0,
                                 const float* __restrict__ inr,
                                 unsigned short* __restrict__ out,
                                 int R, int C) {
  __shared__ float tile[32][33];
  int z = blockIdx.z;
  const float* in = (z == 0) ? in0 : (inr + (long)(z - 1) * R * C);
  unsigned short* o = out + (long)z * R * C;
  int c0 = blockIdx.x * 32;
  int r0 = blockIdx.y * 32;
  int tx = threadIdx.x, ty = threadIdx.y; // (32,8)
#pragma unroll
  for (int k = 0; k < 4; ++k)
    tile[ty + 8 * k][tx] = in[(long)(r0 + ty + 8 * k) * C + c0 + tx];
  __syncthreads();
#pragma unroll
  for (int k = 0; k < 4; ++k)
    o[(long)(c0 + ty + 8 * k) * R + r0 + tx] = f2bf(tile[tx][ty + 8 * k]);
}

// ---------------- gating: fp64 dot, sigmoid, top-2, emit sort keys ----------------
__global__ void k_gating(const float* __restrict__ x,
                         const float* __restrict__ gw,   // [DMODEL][NEXP]
                         const float* __restrict__ bias, // [NEXP]
                         u64* __restrict__ keys) {       // [NEXP][TOKS]
  int wave = threadIdx.x >> 6;
  int lane = threadIdx.x & 63;
  int t = blockIdx.x * 4 + wave;
  const float* xr = x + (long)t * DMODEL;
  double acc[NEXP];
#pragma unroll
  for (int e = 0; e < NEXP; ++e) acc[e] = 0.0;
  for (int i = lane; i < DMODEL; i += 64) {
    double xv = (double)xr[i];
    const float* g = gw + (long)i * NEXP;
#pragma unroll
    for (int e = 0; e < NEXP; ++e) acc[e] += xv * (double)g[e];
  }
#pragma unroll
  for (int e = 0; e < NEXP; ++e) {
    for (int off = 32; off > 0; off >>= 1)
      acc[e] += __shfl_down(acc[e], off, 64);
  }
  if (lane == 0) {
    float aff[NEXP];
#pragma unroll
    for (int e = 0; e < NEXP; ++e) {
      double lg = acc[e] + (double)bias[e];
      aff[e] = (float)(1.0 / (1.0 + exp(-lg)));
    }
    int i1 = 0;
    for (int e = 1; e < NEXP; ++e) if (aff[e] > aff[i1]) i1 = e;
    int i2 = -1;
    for (int e = 0; e < NEXP; ++e) {
      if (e == i1) continue;
      if (i2 < 0 || aff[e] > aff[i2]) i2 = e;
    }
#pragma unroll
    for (int e = 0; e < NEXP; ++e) {
      u64 key = (u64)(0xFFFFFFFFu - (unsigned)t);
      if (e == i1 || e == i2) key |= ((u64)__float_as_uint(aff[e])) << 32;
      keys[(long)e * TOKS + t] = key;
    }
  }
}

// ---------------- per-expert bitonic sort (desc) + capacity selection ----------------
__global__ __launch_bounds__(1024) void k_sort_select(
    const u64* __restrict__ keys, int* __restrict__ sel,
    float* __restrict__ selw) {
  __shared__ u64 s[TOKS];
  int e = blockIdx.x;
  int tid = threadIdx.x;
  for (int i = tid; i < TOKS; i += 1024) s[i] = keys[(long)e * TOKS + i];
  __syncthreads();
  for (int k = 2; k <= TOKS; k <<= 1) {
    for (int j = k >> 1; j > 0; j >>= 1) {
      for (int ii = tid; ii < TOKS; ii += 1024) {
        int ixj = ii ^ j;
        if (ixj > ii) {
          u64 a = s[ii], b = s[ixj];
          bool descRegion = ((ii & k) == 0);
          bool doSwap = descRegion ? (a < b) : (a > b);
          if (doSwap) { s[ii] = b; s[ixj] = a; }
        }
      }
      __syncthreads();
    }
  }
  for (int i = tid; i < CAPP; i += 1024) {
    u64 key = s[i];
    unsigned vb = (unsigned)(key >> 32);
    int tok = (int)(0xFFFFFFFFu - (unsigned)(key & 0xFFFFFFFFull));
    float w = (i < CAP && vb != 0u) ? __uint_as_float(vb) : 0.0f;
    sel[e * CAPP + i] = tok;
    selw[e * CAPP + i] = w;
  }
}

// ---------------- SwiGLU activation: h[rows][2F] -> a[rows][F] ----------------
__global__ void k_act(const unsigned short* __restrict__ h,
                      unsigned short* __restrict__ a, int rows, int F) {
  int fw = F / 8;
  long total = (long)rows * fw;
  long idx = (long)blockIdx.x * blockDim.x + threadIdx.x;
  long stride = (long)gridDim.x * blockDim.x;
  for (; idx < total; idx += stride) {
    long t = idx / fw;
    int f = (int)(idx % fw) * 8;
    const unsigned short* hr = h + t * (2L * F);
    ushort8_t x1 = *(const ushort8_t*)&hr[f];
    ushort8_t x2 = *(const ushort8_t*)&hr[F + f];
    ushort8_t o;
#pragma unroll
    for (int j = 0; j < 8; ++j) {
      float v1 = bf2f(x1[j]);
      float v2 = bf2f(x2[j]);
      float s = v2 / (1.0f + __expf(-v2));
      o[j] = f2bf(v1 * s);
    }
    *(ushort8_t*)&a[t * F + f] = o;
  }
}

// ---------------- 256x256 8-phase GEMM (m201 template): C = A[M,K] * B[N,K]^T ----------------
// 512 thr = 8 waves (2M x 4N), per-wave 128x64. BK=64, 2 K-tiles per 8 phases.
// LDS: 8 segments x 16 KB = 2 dbuf x {A0,A1,B0,B1}. vmcnt(6) at group entry only.
// Group T (d=T&1): ph0 stage B0(T+1); ph1 stage B1(T+1); ph3 stage A0,A1(T+2).
// T2 swizzle: lds byte ^= (row&7)<<4, pre-swizzled global source, swizzled ds_read.
// EPI: 0 -> bf16 C (+z*strideC); 1 -> fp32 C; 2 -> weighted atomicAdd scatter.
template <int EPI, bool GATHER>
__global__ __launch_bounds__(512, 2) void k_gemm8p(
    const unsigned short* __restrict__ Abase,
    const unsigned short* __restrict__ Bbase,
    unsigned short* __restrict__ Cbf, float* __restrict__ Cf32,
    const int* __restrict__ sel, const float* __restrict__ selw,
    int N, int K, long strideA, long strideB, long strideC) {
  extern __shared__ unsigned short lds[];  // 8 * 8192 shorts = 128 KiB
  const int tid = threadIdx.x;
  const int w = tid >> 6;
  const int lane = tid & 63;

  // T1: XCD-aware bijective swizzle (grids are multiples of 8)
  long lin = blockIdx.x + (long)gridDim.x * (blockIdx.y + (long)gridDim.y * blockIdx.z);
  long nwg = (long)gridDim.x * gridDim.y * gridDim.z;
  long swz = (lin & 7) * (nwg >> 3) + (lin >> 3);
  int bx = (int)(swz % gridDim.x);
  long rem = swz / gridDim.x;
  int by = (int)(rem % gridDim.y);
  int z = (int)(rem / gridDim.y);

  const long m0 = (long)by * 256;
  const long n0 = (long)bx * 256;
  const unsigned short* A = Abase + (GATHER ? 0L : (long)z * strideA);
  const unsigned short* Bm = Bbase + (long)z * strideB;

  const int wr = w >> 2;  // 0..1 : M half
  const int wc = w & 3;   // 0..3 : N quarter
  const int lr = lane & 15;
  const int kq = lane >> 4;

  // ---- staging source pointers (pre-swizzled global col; LDS dest linear) ----
  const unsigned short* aP[2][2];
  const unsigned short* bP[2][2];
  int dstOff[2];
#pragma unroll
  for (int j = 0; j < 2; ++j) {
    int L = w * 128 + j * 64 + lane;          // 0..1023 linear slot in segment
    int r = L >> 3;                           // row 0..127
    int cEl = ((L & 7) * 8) ^ ((r & 7) * 8);  // swizzled col (elements)
    dstOff[j] = (w * 2 + j) * 512;            // shorts, wave-uniform base
#pragma unroll
    for (int h = 0; h < 2; ++h) {
      long ar = GATHER ? (long)sel[z * CAPP + (int)m0 + h * 128 + r]
                       : (m0 + h * 128 + r);
      aP[h][j] = A + ar * (long)K + cEl;
      bP[h][j] = Bm + (n0 + h * 128 + r) * (long)K + cEl;
    }
  }

  auto STAGE = [&](int seg, int d, int ts) {
    unsigned short* base = lds + ((d << 2) + seg) * 8192;
    const unsigned short *p0, *p1;
    if (seg < 2) { p0 = aP[seg][0]; p1 = aP[seg][1]; }
    else         { p0 = bP[seg - 2][0]; p1 = bP[seg - 2][1]; }
    long ko = (long)ts * 64;
    gload_lds16(p0 + ko, base + dstOff[0]);
    gload_lds16(p1 + ko, base + dstOff[1]);
  };

  // ---- swizzled LDS read offsets ----
  const int aSegT = wr;            // A half by wave M-half
  const int bSegT = 2 + (wc >> 1); // B half by wave N-half
  const int colSw0 = (kq * 8) ^ ((lr & 7) * 8);        // kk=0
  const int colSw1 = (32 + kq * 8) ^ ((lr & 7) * 8);   // kk=1
  const int bRow = (wc & 1) * 64 + lr;                 // + n*16

  const int nk = K >> 6;

  // prologue: A(0), B(0), A(1)
  STAGE(0, 0, 0); STAGE(1, 0, 0); STAGE(2, 0, 0); STAGE(3, 0, 0);
  STAGE(0, 1, 1); STAGE(1, 1, 1);

  f32x4 acc[8][4] = {};

#pragma unroll 1
  for (int T = 0; T < nk; ++T) {
    const int d = T & 1, dn = d ^ 1;
    int t1 = T + 1; if (t1 >= nk) t1 -= nk;  // tail: dummy restage (count-preserving)
    int t2 = T + 2; if (t2 >= nk) t2 -= nk;
    const unsigned short* aSeg = lds + ((d << 2) + aSegT) * 8192;
    const unsigned short* bSeg = lds + ((d << 2) + bSegT) * 8192;
    bf16x8 af[8], bf0, bf1;

    // ---------- phase 0: stage B0(T+1); vmcnt(6); A kk0 + B n0,n1 kk0 ----------
    STAGE(2, dn, t1);
    asm volatile("s_waitcnt vmcnt(6)" ::: "memory");
    __builtin_amdgcn_sched_barrier(0);
    __builtin_amdgcn_s_barrier();
    __builtin_amdgcn_sched_barrier(0);
#pragma unroll
    for (int m = 0; m < 8; ++m)
      af[m] = *(const bf16x8*)&aSeg[(m * 16 + lr) * 64 + colSw0];
    bf0 = *(const bf16x8*)&bSeg[(bRow + 0) * 64 + colSw0];
    bf1 = *(const bf16x8*)&bSeg[(bRow + 16) * 64 + colSw0];
    asm volatile("s_waitcnt lgkmcnt(0)" ::: "memory");
    __builtin_amdgcn_sched_barrier(0);
    __builtin_amdgcn_s_setprio(1);
#pragma unroll
    for (int m = 0; m < 8; ++m) {
      acc[m][0] = MFMA16(af[m], bf0, acc[m][0]);
      acc[m][1] = MFMA16(af[m], bf1, acc[m][1]);
    }
    __builtin_amdgcn_s_setprio(0);
    __builtin_amdgcn_sched_barrier(0);
    __builtin_amdgcn_s_barrier();
    __builtin_amdgcn_sched_barrier(0);

    // ---------- phase 1: stage B1(T+1); B n2,n3 kk0 ----------
    STAGE(3, dn, t1);
    bf0 = *(const bf16x8*)&bSeg[(bRow + 32) * 64 + colSw0];
    bf1 = *(const bf16x8*)&bSeg[(bRow + 48) * 64 + colSw0];
    asm volatile("s_waitcnt lgkmcnt(0)" ::: "memory");
    __builtin_amdgcn_sched_barrier(0);
    __builtin_amdgcn_s_setprio(1);
#pragma unroll
    for (int m = 0; m < 8; ++m) {
      acc[m][2] = MFMA16(af[m], bf0, acc[m][2]);
      acc[m][3] = MFMA16(af[m], bf1, acc[m][3]);
    }
    __builtin_amdgcn_s_setprio(0);
    __builtin_amdgcn_sched_barrier(0);
    __builtin_amdgcn_s_barrier();
    __builtin_amdgcn_sched_barrier(0);

    // ---------- phase 2: (no stage) A kk1 + B n0,n1 kk1 ----------
#pragma unroll
    for (int m = 0; m < 8; ++m)
      af[m] = *(const bf16x8*)&aSeg[(m * 16 + lr) * 64 + colSw1];
    bf0 = *(const bf16x8*)&bSeg[(bRow + 0) * 64 + colSw1];
    bf1 = *(const bf16x8*)&bSeg[(bRow + 16) * 64 + colSw1];
    asm volatile("s_waitcnt lgkmcnt(0)" ::: "memory");
    __builtin_amdgcn_sched_barrier(0);
    __builtin_amdgcn_s_setprio(1);
#pragma unroll
    for (int m = 0; m < 8; ++m) {
      acc[m][0] = MFMA16(af[m], bf0, acc[m][0]);
      acc[m][1] = MFMA16(af[m], bf1, acc[m][1]);
    }
    __builtin_amdgcn_s_setprio(0);
    __builtin_amdgcn_sched_barrier(0);
    __builtin_amdgcn_s_barrier();
    __builtin_amdgcn_sched_barrier(0);

    // ---------- phase 3: stage A0,A1(T+2); B n2,n3 kk1 ----------
    STAGE(0, d, t2);
    STAGE(1, d, t2);
    bf0 = *(const bf16x8*)&bSeg[(bRow + 32) * 64 + colSw1];
    bf1 = *(const bf16x8*)&bSeg[(bRow + 48) * 64 + colSw1];
    asm volatile("s_waitcnt lgkmcnt(0)" ::: "memory");
    __builtin_amdgcn_sched_barrier(0);
    __builtin_amdgcn_s_setprio(1);
#pragma unroll
    for (int m = 0; m < 8; ++m) {
      acc[m][2] = MFMA16(af[m], bf0, acc[m][2]);
      acc[m][3] = MFMA16(af[m], bf1, acc[m][3]);
    }
    __builtin_amdgcn_s_setprio(0);
    __builtin_amdgcn_sched_barrier(0);
    __builtin_amdgcn_s_barrier();
    __builtin_amdgcn_sched_barrier(0);
  }
  asm volatile("s_waitcnt vmcnt(0)" ::: "memory");

  // ---- epilogue ----
  const int r0q = (lane >> 4) * 4;
  const int cc = lane & 15;
  const long crow0 = m0 + wr * 128;
  const long ccol0 = n0 + wc * 64;

  if (EPI == 0) {
    unsigned short* C = Cbf + (long)z * strideC;
#pragma unroll
    for (int m = 0; m < 8; ++m)
#pragma unroll
      for (int r = 0; r < 4; ++r) {
        long row = crow0 + m * 16 + r0q + r;
#pragma unroll
        for (int n = 0; n < 4; ++n)
          C[row * N + ccol0 + n * 16 + cc] = f2bf(acc[m][n][r]);
      }
  } else if (EPI == 1) {
#pragma unroll
    for (int m = 0; m < 8; ++m)
#pragma unroll
      for (int r = 0; r < 4; ++r) {
        long row = crow0 + m * 16 + r0q + r;
#pragma unroll
        for (int n = 0; n < 4; ++n)
          Cf32[row * N + ccol0 + n * 16 + cc] = acc[m][n][r];
      }
  } else {
#pragma unroll
    for (int m = 0; m < 8; ++m)
#pragma unroll
      for (int r = 0; r < 4; ++r) {
        int srow = (int)crow0 + m * 16 + r0q + r;
        int tok = sel[z * CAPP + srow];
        float wgt = selw[z * CAPP + srow];
        if (wgt != 0.0f) {
#pragma unroll
          for (int n = 0; n < 4; ++n)
            atomicAdd(&Cf32[(long)tok * N + ccol0 + n * 16 + cc],
                      acc[m][n][r] * wgt);
        }
      }
  }
}

extern "C" void kernel_launch(void* const* d_in, const int* in_sizes, int n_in,
                              void* d_out, int out_size, void* d_ws,
                              size_t ws_size, hipStream_t stream) {
  (void)in_sizes; (void)n_in; (void)out_size; (void)ws_size;
  const float* x = (const float*)d_in[0];
  const float* gw = (const float*)d_in[1];
  const float* eb = (const float*)d_in[2];
  const float* sw1 = (const float*)d_in[3];
  const float* sw2 = (const float*)d_in[4];
  const float* rw1 = (const float*)d_in[5];
  const float* rw2 = (const float*)d_in[6];
  float* out = (float*)d_out;

  char* ws = (char*)d_ws;
  size_t off = 0;
  auto alloc = [&](size_t bytes) {
    size_t o = off;
    off += (bytes + 255) & ~(size_t)255;
    return o;
  };
  unsigned short* xb   = (unsigned short*)(ws + alloc((size_t)TOKS * DMODEL * 2));
  unsigned short* w1t  = (unsigned short*)(ws + alloc((size_t)8 * DMODEL * (2 * FD) * 2));
  unsigned short* w2t  = (unsigned short*)(ws + alloc((size_t)8 * DMODEL * FD * 2));
  unsigned short* h_sh = (unsigned short*)(ws + alloc((size_t)TOKS * (2 * FD) * 2));
  unsigned short* a_sh = (unsigned short*)(ws + alloc((size_t)TOKS * FD * 2));
  unsigned short* h_r  = (unsigned short*)(ws + alloc((size_t)NEXP * CAPP * (2 * FD) * 2));
  unsigned short* a_r  = (unsigned short*)(ws + alloc((size_t)NEXP * CAPP * FD * 2));
  u64* keys            = (u64*)(ws + alloc((size_t)NEXP * TOKS * 8));
  int* sel             = (int*)(ws + alloc((size_t)NEXP * CAPP * 4));
  float* selw          = (float*)(ws + alloc((size_t)NEXP * CAPP * 4));

  const size_t LDSB = 131072;  // 8 segments x 16 KiB

  // 1. x -> bf16
  k_convert_x<<<8192, 256, 0, stream>>>(x, xb, (long)TOKS * DMODEL / 4);
  // 2./3. weight transposes
  dim3 tb(32, 8);
  k_transpose_bf16<<<dim3(64, 64, 8), tb, 0, stream>>>(sw1, rw1, w1t, DMODEL, 2 * FD);
  k_transpose_bf16<<<dim3(64, 32, 8), tb, 0, stream>>>(sw2, rw2, w2t, FD, DMODEL);
  // 4. gating
  k_gating<<<TOKS / 4, 256, 0, stream>>>(x, gw, eb, keys);
  // 5. per-expert selection
  k_sort_select<<<NEXP, 1024, 0, stream>>>(keys, sel, selw);
  // 6. shared GEMM1: xb[8192,2048] @ w1t[z=0]^T -> h_sh bf16 [8192,2048]
  k_gemm8p<0, false><<<dim3(8, 32, 1), 512, LDSB, stream>>>(
      xb, w1t, h_sh, nullptr, nullptr, nullptr, 2 * FD, DMODEL, 0, 0, 0);
  // 7. shared activation
  k_act<<<2048, 256, 0, stream>>>(h_sh, a_sh, TOKS, FD);
  // 8. shared GEMM2 -> d_out fp32 (full overwrite)
  k_gemm8p<1, false><<<dim3(8, 32, 1), 512, LDSB, stream>>>(
      a_sh, w2t, nullptr, out, nullptr, nullptr, DMODEL, FD, 0, 0, 0);
  // 9. routed GEMM1 (gathered A): z=expert
  k_gemm8p<0, true><<<dim3(8, CAPP / 256, NEXP), 512, LDSB, stream>>>(
      xb, w1t + (size_t)DMODEL * (2 * FD), h_r, nullptr, sel, nullptr, 2 * FD,
      DMODEL, 0, (long)DMODEL * (2 * FD), (long)CAPP * (2 * FD));
  // 10. routed activation
  k_act<<<2048, 256, 0, stream>>>(h_r, a_r, NEXP * CAPP, FD);
  // 11. routed GEMM2 with weighted atomic scatter into d_out
  k_gemm8p<2, false><<<dim3(8, CAPP / 256, NEXP), 512, LDSB, stream>>>(
      a_r, w2t + (size_t)DMODEL * FD, nullptr, out, sel, selw, DMODEL, FD,
      (long)CAPP * FD, (long)DMODEL * FD, 0);
}

// Round 4
// 576.717 us; speedup vs baseline: 1.1769x; 1.0577x over previous
//
#include <hip/hip_runtime.h>
#include <hip/hip_bf16.h>

typedef unsigned long long u64;
typedef __bf16 bf16x8 __attribute__((ext_vector_type(8)));
typedef float f32x4 __attribute__((ext_vector_type(4)));
typedef unsigned short ushort8_t __attribute__((ext_vector_type(8)));

#define TOKS 8192
#define DMODEL 2048
#define FD 1024
#define NEXP 7
#define CAP 1170
#define CAPP 1280

#define MFMA16(a, b, c) __builtin_amdgcn_mfma_f32_16x16x32_bf16(a, b, c, 0, 0, 0)

__device__ __forceinline__ unsigned short f2bf(float f) {
  __hip_bfloat16 b = __float2bfloat16(f);
  return __builtin_bit_cast(unsigned short, b);
}
__device__ __forceinline__ float bf2f(unsigned short u) {
  __hip_bfloat16 b = __builtin_bit_cast(__hip_bfloat16, u);
  return __bfloat162float(b);
}
__device__ __forceinline__ void gload_lds16(const void* g, void* l) {
  __builtin_amdgcn_global_load_lds(
      (const __attribute__((address_space(1))) void*)g,
      (__attribute__((address_space(3))) void*)l, 16, 0, 0);
}

// ---------------- x fp32 -> bf16 ----------------
__global__ void k_convert_x(const float* __restrict__ x,
                            unsigned short* __restrict__ xb, long n4) {
  long i = (long)blockIdx.x * blockDim.x + threadIdx.x;
  long stride = (long)gridDim.x * blockDim.x;
  for (; i < n4; i += stride) {
    float4 v = ((const float4*)x)[i];
    ushort4 o;
    o.x = f2bf(v.x); o.y = f2bf(v.y); o.z = f2bf(v.z); o.w = f2bf(v.w);
    ((ushort4*)xb)[i] = o;
  }
}

// ---------------- transpose fp32 [R][C] -> bf16 [C][R], batched z ----------------
// PERM: interleave output rows in 16-blocks: orig col c -> row ((c&1023)>>4)*32 + (c>>10)*16 + (c&15)
// so GEMM1 tiles see x1-block / x2-block alternating every 16 cols (SwiGLU fusion).
template <bool PERM>
__global__ void k_transpose_bf16(const float* __restrict__ in0,
                                 const float* __restrict__ inr,
                                 unsigned short* __restrict__ out,
                                 int R, int C) {
  __shared__ float tile[32][33];
  int z = blockIdx.z;
  const float* in = (z == 0) ? in0 : (inr + (long)(z - 1) * R * C);
  unsigned short* o = out + (long)z * R * C;
  int c0 = blockIdx.x * 32;
  int r0 = blockIdx.y * 32;
  int tx = threadIdx.x, ty = threadIdx.y; // (32,8)
#pragma unroll
  for (int k = 0; k < 4; ++k)
    tile[ty + 8 * k][tx] = in[(long)(r0 + ty + 8 * k) * C + c0 + tx];
  __syncthreads();
#pragma unroll
  for (int k = 0; k < 4; ++k) {
    int c = c0 + ty + 8 * k;
    long orow = PERM ? (long)(((c & 1023) >> 4) * 32 + ((c >> 10) << 4) + (c & 15))
                     : (long)c;
    o[orow * R + r0 + tx] = f2bf(tile[tx][ty + 8 * k]);
  }
}

// ---------------- gating: fp64 dot, sigmoid, top-2, emit sort keys ----------------
__global__ void k_gating(const float* __restrict__ x,
                         const float* __restrict__ gw,   // [DMODEL][NEXP]
                         const float* __restrict__ bias, // [NEXP]
                         u64* __restrict__ keys) {       // [NEXP][TOKS]
  int wave = threadIdx.x >> 6;
  int lane = threadIdx.x & 63;
  int t = blockIdx.x * 4 + wave;
  const float* xr = x + (long)t * DMODEL;
  double acc[NEXP];
#pragma unroll
  for (int e = 0; e < NEXP; ++e) acc[e] = 0.0;
  for (int i = lane; i < DMODEL; i += 64) {
    double xv = (double)xr[i];
    const float* g = gw + (long)i * NEXP;
#pragma unroll
    for (int e = 0; e < NEXP; ++e) acc[e] += xv * (double)g[e];
  }
#pragma unroll
  for (int e = 0; e < NEXP; ++e) {
    for (int off = 32; off > 0; off >>= 1)
      acc[e] += __shfl_down(acc[e], off, 64);
  }
  if (lane == 0) {
    float aff[NEXP];
#pragma unroll
    for (int e = 0; e < NEXP; ++e) {
      double lg = acc[e] + (double)bias[e];
      aff[e] = (float)(1.0 / (1.0 + exp(-lg)));
    }
    int i1 = 0;
    for (int e = 1; e < NEXP; ++e) if (aff[e] > aff[i1]) i1 = e;
    int i2 = -1;
    for (int e = 0; e < NEXP; ++e) {
      if (e == i1) continue;
      if (i2 < 0 || aff[e] > aff[i2]) i2 = e;
    }
#pragma unroll
    for (int e = 0; e < NEXP; ++e) {
      u64 key = (u64)(0xFFFFFFFFu - (unsigned)t);
      if (e == i1 || e == i2) key |= ((u64)__float_as_uint(aff[e])) << 32;
      keys[(long)e * TOKS + t] = key;
    }
  }
}

// ---------------- per-expert bitonic sort (desc) + capacity selection ----------------
__global__ __launch_bounds__(1024) void k_sort_select(
    const u64* __restrict__ keys, int* __restrict__ sel,
    float* __restrict__ selw) {
  __shared__ u64 s[TOKS];
  int e = blockIdx.x;
  int tid = threadIdx.x;
  for (int i = tid; i < TOKS; i += 1024) s[i] = keys[(long)e * TOKS + i];
  __syncthreads();
  for (int k = 2; k <= TOKS; k <<= 1) {
    for (int j = k >> 1; j > 0; j >>= 1) {
      for (int ii = tid; ii < TOKS; ii += 1024) {
        int ixj = ii ^ j;
        if (ixj > ii) {
          u64 a = s[ii], b = s[ixj];
          bool descRegion = ((ii & k) == 0);
          bool doSwap = descRegion ? (a < b) : (a > b);
          if (doSwap) { s[ii] = b; s[ixj] = a; }
        }
      }
      __syncthreads();
    }
  }
  for (int i = tid; i < CAPP; i += 1024) {
    u64 key = s[i];
    unsigned vb = (unsigned)(key >> 32);
    int tok = (int)(0xFFFFFFFFu - (unsigned)(key & 0xFFFFFFFFull));
    float w = (i < CAP && vb != 0u) ? __uint_as_float(vb) : 0.0f;
    sel[e * CAPP + i] = tok;
    selw[e * CAPP + i] = w;
  }
}

// ---------------- 256x256 2-phase GEMM (verified T3 minimum recipe) ----------------
// 512 thr = 8 waves (2M x 4N), per-wave 128x64. BK=64.
// LDS: 2 buffers x (A 32KB + B 32KB) = 128 KiB dynamic.
// Per K-tile: STAGE(next) -> ds_read(cur) -> lgkmcnt(0) -> setprio(1) 64 MFMA setprio(0)
//             -> vmcnt(0) -> barrier. Stage latency hides under the MFMA cluster.
// T2 swizzle: 16B col-slot ^= (row&7), pre-swizzled global source, swizzled ds_read.
// EPI: 1 -> fp32 store; 2 -> weighted atomicAdd scatter; 3 -> SwiGLU + bf16 store (N/2 cols).
template <int EPI, bool GATHER>
__global__ __launch_bounds__(512, 2) void k_gemm2ph(
    const unsigned short* __restrict__ Abase,
    const unsigned short* __restrict__ Bbase,
    unsigned short* __restrict__ Cbf, float* __restrict__ Cf32,
    const int* __restrict__ sel, const float* __restrict__ selw,
    int N, int K, long strideA, long strideB, long strideC) {
  extern __shared__ unsigned short lds[];  // 2 * 32768 shorts
  const int tid = threadIdx.x;
  const int w = tid >> 6;
  const int lane = tid & 63;

  // T1: XCD-aware bijective swizzle (grid sizes are multiples of 8)
  long lin = blockIdx.x + (long)gridDim.x * (blockIdx.y + (long)gridDim.y * blockIdx.z);
  long nwg = (long)gridDim.x * gridDim.y * gridDim.z;
  long swz = (lin & 7) * (nwg >> 3) + (lin >> 3);
  int bx = (int)(swz % gridDim.x);
  long rem = swz / gridDim.x;
  int by = (int)(rem % gridDim.y);
  int z = (int)(rem / gridDim.y);

  const long m0 = (long)by * 256;
  const long n0 = (long)bx * 256;
  const unsigned short* A = Abase + (GATHER ? 0L : (long)z * strideA);
  const unsigned short* Bm = Bbase + (long)z * strideB;

  const int wr = w >> 2;  // 0..1 M half
  const int wc = w & 3;   // 0..3 N quarter
  const int lr = lane & 15;
  const int kq = lane >> 4;

  // ---- staging: per thread 4 A-rows + 4 B-rows, pre-swizzled source col ----
  const int srow = (w << 3) + (lane >> 3);              // 0..63, + j*64
  const int scol = (((lane & 7) ^ (lane >> 3)) << 3);   // swizzled col (elements)
  const unsigned short* aPtr[4];
  const unsigned short* bPtr[4];
#pragma unroll
  for (int j = 0; j < 4; ++j) {
    int r = j * 64 + srow;
    long ar = GATHER ? (long)sel[z * CAPP + (int)m0 + r] : (m0 + r);
    aPtr[j] = A + ar * (long)K + scol;
    bPtr[j] = Bm + (n0 + r) * (long)K + scol;
  }
  const int dst0 = tid * 8;  // shorts; + j*4096; A region [0,16384), B [16384,32768)

  auto STAGE = [&](int buf, int t) {
    unsigned short* base = lds + buf * 32768;
    const long ko = (long)t * 64;
#pragma unroll
    for (int j = 0; j < 4; ++j) {
      gload_lds16(aPtr[j] + ko, base + j * 4096 + dst0);
      gload_lds16(bPtr[j] + ko, base + 16384 + j * 4096 + dst0);
    }
  };

  // ---- ds_read offsets (swizzled): slot = (kq + 4*kk) ^ (lr&7) ----
  const int slot0 = (kq ^ (lr & 7)) * 8;
  const int slot1 = ((kq + 4) ^ (lr & 7)) * 8;
  const int aRow = wr * 128 + lr;  // + m*16
  const int bRow = wc * 64 + lr;   // + n*16

  const int nk = K >> 6;

  STAGE(0, 0);
  asm volatile("s_waitcnt vmcnt(0)" ::: "memory");
  __builtin_amdgcn_sched_barrier(0);
  __builtin_amdgcn_s_barrier();
  __builtin_amdgcn_sched_barrier(0);

  f32x4 acc[8][4] = {};
  int cur = 0;

#pragma unroll 1
  for (int t = 0; t < nk; ++t) {
    if (t + 1 < nk) STAGE(cur ^ 1, t + 1);
    const unsigned short* aSeg = lds + cur * 32768;
    const unsigned short* bSeg = aSeg + 16384;
    bf16x8 af[8], bf[4];
    // ---- kk = 0 ----
#pragma unroll
    for (int m = 0; m < 8; ++m)
      af[m] = *(const bf16x8*)&aSeg[(aRow + m * 16) * 64 + slot0];
#pragma unroll
    for (int n = 0; n < 4; ++n)
      bf[n] = *(const bf16x8*)&bSeg[(bRow + n * 16) * 64 + slot0];
    asm volatile("s_waitcnt lgkmcnt(0)" ::: "memory");
    __builtin_amdgcn_sched_barrier(0);
    __builtin_amdgcn_s_setprio(1);
#pragma unroll
    for (int m = 0; m < 8; ++m)
#pragma unroll
      for (int n = 0; n < 4; ++n)
        acc[m][n] = MFMA16(af[m], bf[n], acc[m][n]);
    __builtin_amdgcn_s_setprio(0);
    // ---- kk = 1 ----
#pragma unroll
    for (int m = 0; m < 8; ++m)
      af[m] = *(const bf16x8*)&aSeg[(aRow + m * 16) * 64 + slot1];
#pragma unroll
    for (int n = 0; n < 4; ++n)
      bf[n] = *(const bf16x8*)&bSeg[(bRow + n * 16) * 64 + slot1];
    asm volatile("s_waitcnt lgkmcnt(0)" ::: "memory");
    __builtin_amdgcn_sched_barrier(0);
    __builtin_amdgcn_s_setprio(1);
#pragma unroll
    for (int m = 0; m < 8; ++m)
#pragma unroll
      for (int n = 0; n < 4; ++n)
        acc[m][n] = MFMA16(af[m], bf[n], acc[m][n]);
    __builtin_amdgcn_s_setprio(0);
    // next tile staged & all reads retired before anyone restages this buffer
    asm volatile("s_waitcnt vmcnt(0)" ::: "memory");
    __builtin_amdgcn_sched_barrier(0);
    __builtin_amdgcn_s_barrier();
    __builtin_amdgcn_sched_barrier(0);
    cur ^= 1;
  }

  // ---- epilogue ----
  const int r0q = (lane >> 4) * 4;
  const int cc = lane & 15;
  const long crow0 = m0 + wr * 128;
  const long ccol0 = n0 + wc * 64;

  if (EPI == 1) {
#pragma unroll
    for (int m = 0; m < 8; ++m)
#pragma unroll
      for (int r = 0; r < 4; ++r) {
        long row = crow0 + m * 16 + r0q + r;
#pragma unroll
        for (int n = 0; n < 4; ++n)
          Cf32[row * N + ccol0 + n * 16 + cc] = acc[m][n][r];
      }
  } else if (EPI == 2) {
#pragma unroll
    for (int m = 0; m < 8; ++m)
#pragma unroll
      for (int r = 0; r < 4; ++r) {
        int srowi = (int)crow0 + m * 16 + r0q + r;
        int tok = sel[z * CAPP + srowi];
        float wgt = selw[z * CAPP + srowi];
        if (wgt != 0.0f) {
#pragma unroll
          for (int n = 0; n < 4; ++n)
            atomicAdd(&Cf32[(long)tok * N + ccol0 + n * 16 + cc],
                      acc[m][n][r] * wgt);
        }
      }
  } else {  // EPI == 3: SwiGLU fused store, output width N/2
    unsigned short* C = Cbf + (long)z * strideC;
    const int halfN = N >> 1;
    const long gcol0 = (ccol0 >> 1);  // n0/2 + wc*32
#pragma unroll
    for (int m = 0; m < 8; ++m)
#pragma unroll
      for (int r = 0; r < 4; ++r) {
        long row = crow0 + m * 16 + r0q + r;
#pragma unroll
        for (int q = 0; q < 2; ++q) {
          float x1v = acc[m][2 * q][r];
          float x2v = acc[m][2 * q + 1][r];
          float s = x2v / (1.0f + __expf(-x2v));
          C[row * halfN + gcol0 + q * 16 + cc] = f2bf(x1v * s);
        }
      }
  }
}

extern "C" void kernel_launch(void* const* d_in, const int* in_sizes, int n_in,
                              void* d_out, int out_size, void* d_ws,
                              size_t ws_size, hipStream_t stream) {
  (void)in_sizes; (void)n_in; (void)out_size; (void)ws_size;
  const float* x = (const float*)d_in[0];
  const float* gw = (const float*)d_in[1];
  const float* eb = (const float*)d_in[2];
  const float* sw1 = (const float*)d_in[3];
  const float* sw2 = (const float*)d_in[4];
  const float* rw1 = (const float*)d_in[5];
  const float* rw2 = (const float*)d_in[6];
  float* out = (float*)d_out;

  char* ws = (char*)d_ws;
  size_t off = 0;
  auto alloc = [&](size_t bytes) {
    size_t o = off;
    off += (bytes + 255) & ~(size_t)255;
    return o;
  };
  unsigned short* xb  = (unsigned short*)(ws + alloc((size_t)TOKS * DMODEL * 2));
  unsigned short* w1t = (unsigned short*)(ws + alloc((size_t)8 * DMODEL * (2 * FD) * 2));
  unsigned short* w2t = (unsigned short*)(ws + alloc((size_t)8 * DMODEL * FD * 2));
  unsigned short* a_sh = (unsigned short*)(ws + alloc((size_t)TOKS * FD * 2));
  unsigned short* a_r  = (unsigned short*)(ws + alloc((size_t)NEXP * CAPP * FD * 2));
  u64* keys = (u64*)(ws + alloc((size_t)NEXP * TOKS * 8));
  int* sel  = (int*)(ws + alloc((size_t)NEXP * CAPP * 4));
  float* selw = (float*)(ws + alloc((size_t)NEXP * CAPP * 4));

  const size_t LDSB = 131072;  // 2 x 64 KiB buffers

  // 1. x -> bf16
  k_convert_x<<<8192, 256, 0, stream>>>(x, xb, (long)TOKS * DMODEL / 4);
  // 2./3. weight transposes (w1 with x1/x2 16-block interleave for fused SwiGLU)
  dim3 tb(32, 8);
  k_transpose_bf16<true><<<dim3(64, 64, 8), tb, 0, stream>>>(sw1, rw1, w1t, DMODEL, 2 * FD);
  k_transpose_bf16<false><<<dim3(64, 32, 8), tb, 0, stream>>>(sw2, rw2, w2t, FD, DMODEL);
  // 4. gating
  k_gating<<<TOKS / 4, 256, 0, stream>>>(x, gw, eb, keys);
  // 5. per-expert selection
  k_sort_select<<<NEXP, 1024, 0, stream>>>(keys, sel, selw);
  // 6. shared GEMM1 + fused SwiGLU: xb @ w1t[0]^T -> a_sh bf16 [8192,1024]
  k_gemm2ph<3, false><<<dim3(8, 32, 1), 512, LDSB, stream>>>(
      xb, w1t, a_sh, nullptr, nullptr, nullptr, 2 * FD, DMODEL, 0, 0, 0);
  // 7. shared GEMM2 -> d_out fp32 (full overwrite)
  k_gemm2ph<1, false><<<dim3(8, 32, 1), 512, LDSB, stream>>>(
      a_sh, w2t, nullptr, out, nullptr, nullptr, DMODEL, FD, 0, 0, 0);
  // 8. routed GEMM1 + fused SwiGLU (gathered A): -> a_r bf16 [7][1280][1024]
  k_gemm2ph<3, true><<<dim3(8, CAPP / 256, NEXP), 512, LDSB, stream>>>(
      xb, w1t + (size_t)DMODEL * (2 * FD), a_r, nullptr, sel, nullptr, 2 * FD,
      DMODEL, 0, (long)DMODEL * (2 * FD), (long)CAPP * FD);
  // 9. routed GEMM2 with weighted atomic scatter into d_out
  k_gemm2ph<2, false><<<dim3(8, CAPP / 256, NEXP), 512, LDSB, stream>>>(
      a_r, w2t + (size_t)DMODEL * FD, nullptr, out, sel, selw, DMODEL, FD,
      (long)CAPP * FD, (long)DMODEL * FD, 0);
}

// Round 5
// 531.178 us; speedup vs baseline: 1.2778x; 1.0857x over previous
//
#include <hip/hip_runtime.h>
#include <hip/hip_bf16.h>

typedef unsigned long long u64;
typedef __bf16 bf16x8 __attribute__((ext_vector_type(8)));
typedef float f32x4 __attribute__((ext_vector_type(4)));
typedef unsigned short ushort8_t __attribute__((ext_vector_type(8)));

#define TOKS 8192
#define DMODEL 2048
#define FD 1024
#define NEXP 7
#define CAP 1170
#define CAPP 1280

#define MFMA16(a, b, c) __builtin_amdgcn_mfma_f32_16x16x32_bf16(a, b, c, 0, 0, 0)

__device__ __forceinline__ unsigned short f2bf(float f) {
  __hip_bfloat16 b = __float2bfloat16(f);
  return __builtin_bit_cast(unsigned short, b);
}
__device__ __forceinline__ float bf2f(unsigned short u) {
  __hip_bfloat16 b = __builtin_bit_cast(__hip_bfloat16, u);
  return __bfloat162float(b);
}
__device__ __forceinline__ void gload_lds16(const void* g, void* l) {
  __builtin_amdgcn_global_load_lds(
      (const __attribute__((address_space(1))) void*)g,
      (__attribute__((address_space(3))) void*)l, 16, 0, 0);
}

// ---------------- x fp32 -> bf16 ----------------
__global__ void k_convert_x(const float* __restrict__ x,
                            unsigned short* __restrict__ xb, long n4) {
  long i = (long)blockIdx.x * blockDim.x + threadIdx.x;
  long stride = (long)gridDim.x * blockDim.x;
  for (; i < n4; i += stride) {
    float4 v = ((const float4*)x)[i];
    ushort4 o;
    o.x = f2bf(v.x); o.y = f2bf(v.y); o.z = f2bf(v.z); o.w = f2bf(v.w);
    ((ushort4*)xb)[i] = o;
  }
}

// ---------------- transpose fp32 [R][C] -> bf16 [C][R], batched z ----------------
// PERM: interleave output rows in 16-blocks: orig col c -> row ((c&1023)>>4)*32 + (c>>10)*16 + (c&15)
// so GEMM1 tiles see x1-block / x2-block alternating every 16 cols (SwiGLU fusion).
template <bool PERM>
__global__ void k_transpose_bf16(const float* __restrict__ in0,
                                 const float* __restrict__ inr,
                                 unsigned short* __restrict__ out,
                                 int R, int C) {
  __shared__ float tile[32][33];
  int z = blockIdx.z;
  const float* in = (z == 0) ? in0 : (inr + (long)(z - 1) * R * C);
  unsigned short* o = out + (long)z * R * C;
  int c0 = blockIdx.x * 32;
  int r0 = blockIdx.y * 32;
  int tx = threadIdx.x, ty = threadIdx.y; // (32,8)
#pragma unroll
  for (int k = 0; k < 4; ++k)
    tile[ty + 8 * k][tx] = in[(long)(r0 + ty + 8 * k) * C + c0 + tx];
  __syncthreads();
#pragma unroll
  for (int k = 0; k < 4; ++k) {
    int c = c0 + ty + 8 * k;
    long orow = PERM ? (long)(((c & 1023) >> 4) * 32 + ((c >> 10) << 4) + (c & 15))
                     : (long)c;
    o[orow * R + r0 + tx] = f2bf(tile[tx][ty + 8 * k]);
  }
}

// ---------------- gating: fp64 dot, sigmoid, top-2, emit sort keys ----------------
__global__ void k_gating(const float* __restrict__ x,
                         const float* __restrict__ gw,   // [DMODEL][NEXP]
                         const float* __restrict__ bias, // [NEXP]
                         u64* __restrict__ keys) {       // [NEXP][TOKS]
  int wave = threadIdx.x >> 6;
  int lane = threadIdx.x & 63;
  int t = blockIdx.x * 4 + wave;
  const float* xr = x + (long)t * DMODEL;
  double acc[NEXP];
#pragma unroll
  for (int e = 0; e < NEXP; ++e) acc[e] = 0.0;
  for (int i = lane; i < DMODEL; i += 64) {
    double xv = (double)xr[i];
    const float* g = gw + (long)i * NEXP;
#pragma unroll
    for (int e = 0; e < NEXP; ++e) acc[e] += xv * (double)g[e];
  }
#pragma unroll
  for (int e = 0; e < NEXP; ++e) {
    for (int off = 32; off > 0; off >>= 1)
      acc[e] += __shfl_down(acc[e], off, 64);
  }
  if (lane == 0) {
    float aff[NEXP];
#pragma unroll
    for (int e = 0; e < NEXP; ++e) {
      double lg = acc[e] + (double)bias[e];
      aff[e] = (float)(1.0 / (1.0 + exp(-lg)));
    }
    int i1 = 0;
    for (int e = 1; e < NEXP; ++e) if (aff[e] > aff[i1]) i1 = e;
    int i2 = -1;
    for (int e = 0; e < NEXP; ++e) {
      if (e == i1) continue;
      if (i2 < 0 || aff[e] > aff[i2]) i2 = e;
    }
#pragma unroll
    for (int e = 0; e < NEXP; ++e) {
      u64 key = (u64)(0xFFFFFFFFu - (unsigned)t);
      if (e == i1 || e == i2) key |= ((u64)__float_as_uint(aff[e])) << 32;
      keys[(long)e * TOKS + t] = key;
    }
  }
}

// ---------------- per-expert radix-select of top-CAP keys ----------------
// Keys are distinct (low 32 bits = ~token), so the CAP-th largest key T is unique
// and {selected} == {key >= T}. Slot order is irrelevant (output is scatter-add
// by token), so we append selected tokens in arbitrary order via an LDS counter.
__global__ __launch_bounds__(1024) void k_select(
    const u64* __restrict__ keys, int* __restrict__ sel,
    float* __restrict__ selw) {
  __shared__ unsigned hist[256];
  __shared__ u64 s_prefix;
  __shared__ unsigned s_k;
  __shared__ unsigned s_cnt;
  const int e = blockIdx.x;
  const u64* kk = keys + (long)e * TOKS;
  const int tid = threadIdx.x;
  if (tid == 0) { s_prefix = 0; s_k = CAP; s_cnt = 0; }
  __syncthreads();
  for (int shift = 56; shift >= 0; shift -= 8) {
    if (tid < 256) hist[tid] = 0;
    __syncthreads();
    u64 pref = s_prefix;
    for (int i = tid; i < TOKS; i += 1024) {
      u64 key = kk[i];
      bool match = (shift == 56) || ((key >> (shift + 8)) == pref);
      if (match) atomicAdd(&hist[(unsigned)(key >> shift) & 255u], 1u);
    }
    __syncthreads();
    if (tid == 0) {
      unsigned k = s_k, cum = 0;
      for (int b = 255; b >= 0; --b) {
        unsigned c = hist[b];
        if (cum + c >= k) {
          s_prefix = (s_prefix << 8) | (unsigned)b;
          s_k = k - cum;
          break;
        }
        cum += c;
      }
    }
    __syncthreads();
  }
  const u64 T = s_prefix;  // exact CAP-th largest key
  for (int i = tid; i < TOKS; i += 1024) {
    u64 key = kk[i];
    if (key >= T) {
      unsigned p = atomicAdd(&s_cnt, 1u);
      int tok = (int)(0xFFFFFFFFu - (unsigned)(key & 0xFFFFFFFFull));
      unsigned vb = (unsigned)(key >> 32);
      sel[e * CAPP + p] = tok;
      selw[e * CAPP + p] = vb ? __uint_as_float(vb) : 0.0f;
    }
  }
  for (int i = CAP + tid; i < CAPP; i += 1024) {
    sel[e * CAPP + i] = 0;
    selw[e * CAPP + i] = 0.0f;
  }
}

// ---------------- 256x256 2-phase GEMM (verified T3 minimum recipe) ----------------
// 512 thr = 8 waves (2M x 4N), per-wave 128x64. BK=64.
// LDS: 2 buffers x (A 32KB + B 32KB) = 128 KiB dynamic.
// Per K-tile: STAGE(next) -> ds_read(cur) -> lgkmcnt(0) -> setprio(1) 64 MFMA setprio(0)
//             -> vmcnt(0) -> barrier. Stage latency hides under the MFMA cluster.
// T2 swizzle: 16B col-slot ^= (row&7), pre-swizzled global source, swizzled ds_read.
// EPI: 1 -> fp32 store; 2 -> weighted atomicAdd scatter; 3 -> SwiGLU + bf16 store (N/2 cols).
template <int EPI, bool GATHER>
__global__ __launch_bounds__(512, 2) void k_gemm2ph(
    const unsigned short* __restrict__ Abase,
    const unsigned short* __restrict__ Bbase,
    unsigned short* __restrict__ Cbf, float* __restrict__ Cf32,
    const int* __restrict__ sel, const float* __restrict__ selw,
    int N, int K, long strideA, long strideB, long strideC) {
  extern __shared__ unsigned short lds[];  // 2 * 32768 shorts
  const int tid = threadIdx.x;
  const int w = tid >> 6;
  const int lane = tid & 63;

  // T1: XCD-aware bijective swizzle (grid sizes are multiples of 8)
  long lin = blockIdx.x + (long)gridDim.x * (blockIdx.y + (long)gridDim.y * blockIdx.z);
  long nwg = (long)gridDim.x * gridDim.y * gridDim.z;
  long swz = (lin & 7) * (nwg >> 3) + (lin >> 3);
  int bx = (int)(swz % gridDim.x);
  long rem = swz / gridDim.x;
  int by = (int)(rem % gridDim.y);
  int z = (int)(rem / gridDim.y);

  const long m0 = (long)by * 256;
  const long n0 = (long)bx * 256;
  const unsigned short* A = Abase + (GATHER ? 0L : (long)z * strideA);
  const unsigned short* Bm = Bbase + (long)z * strideB;

  const int wr = w >> 2;  // 0..1 M half
  const int wc = w & 3;   // 0..3 N quarter
  const int lr = lane & 15;
  const int kq = lane >> 4;

  // ---- staging: per thread 4 A-rows + 4 B-rows, pre-swizzled source col ----
  const int srow = (w << 3) + (lane >> 3);              // 0..63, + j*64
  const int scol = (((lane & 7) ^ (lane >> 3)) << 3);   // swizzled col (elements)
  const unsigned short* aPtr[4];
  const unsigned short* bPtr[4];
#pragma unroll
  for (int j = 0; j < 4; ++j) {
    int r = j * 64 + srow;
    long ar = GATHER ? (long)sel[z * CAPP + (int)m0 + r] : (m0 + r);
    aPtr[j] = A + ar * (long)K + scol;
    bPtr[j] = Bm + (n0 + r) * (long)K + scol;
  }
  const int dst0 = tid * 8;  // shorts; + j*4096; A region [0,16384), B [16384,32768)

  auto STAGE = [&](int buf, int t) {
    unsigned short* base = lds + buf * 32768;
    const long ko = (long)t * 64;
#pragma unroll
    for (int j = 0; j < 4; ++j) {
      gload_lds16(aPtr[j] + ko, base + j * 4096 + dst0);
      gload_lds16(bPtr[j] + ko, base + 16384 + j * 4096 + dst0);
    }
  };

  // ---- ds_read offsets (swizzled): slot = (kq + 4*kk) ^ (lr&7) ----
  const int slot0 = (kq ^ (lr & 7)) * 8;
  const int slot1 = ((kq + 4) ^ (lr & 7)) * 8;
  const int aRow = wr * 128 + lr;  // + m*16
  const int bRow = wc * 64 + lr;   // + n*16

  const int nk = K >> 6;

  STAGE(0, 0);
  asm volatile("s_waitcnt vmcnt(0)" ::: "memory");
  __builtin_amdgcn_sched_barrier(0);
  __builtin_amdgcn_s_barrier();
  __builtin_amdgcn_sched_barrier(0);

  f32x4 acc[8][4] = {};
  int cur = 0;

#pragma unroll 1
  for (int t = 0; t < nk; ++t) {
    if (t + 1 < nk) STAGE(cur ^ 1, t + 1);
    const unsigned short* aSeg = lds + cur * 32768;
    const unsigned short* bSeg = aSeg + 16384;
    bf16x8 af[8], bf[4];
    // ---- kk = 0 ----
#pragma unroll
    for (int m = 0; m < 8; ++m)
      af[m] = *(const bf16x8*)&aSeg[(aRow + m * 16) * 64 + slot0];
#pragma unroll
    for (int n = 0; n < 4; ++n)
      bf[n] = *(const bf16x8*)&bSeg[(bRow + n * 16) * 64 + slot0];
    asm volatile("s_waitcnt lgkmcnt(0)" ::: "memory");
    __builtin_amdgcn_sched_barrier(0);
    __builtin_amdgcn_s_setprio(1);
#pragma unroll
    for (int m = 0; m < 8; ++m)
#pragma unroll
      for (int n = 0; n < 4; ++n)
        acc[m][n] = MFMA16(af[m], bf[n], acc[m][n]);
    __builtin_amdgcn_s_setprio(0);
    // ---- kk = 1 ----
#pragma unroll
    for (int m = 0; m < 8; ++m)
      af[m] = *(const bf16x8*)&aSeg[(aRow + m * 16) * 64 + slot1];
#pragma unroll
    for (int n = 0; n < 4; ++n)
      bf[n] = *(const bf16x8*)&bSeg[(bRow + n * 16) * 64 + slot1];
    asm volatile("s_waitcnt lgkmcnt(0)" ::: "memory");
    __builtin_amdgcn_sched_barrier(0);
    __builtin_amdgcn_s_setprio(1);
#pragma unroll
    for (int m = 0; m < 8; ++m)
#pragma unroll
      for (int n = 0; n < 4; ++n)
        acc[m][n] = MFMA16(af[m], bf[n], acc[m][n]);
    __builtin_amdgcn_s_setprio(0);
    // next tile staged & all reads retired before anyone restages this buffer
    asm volatile("s_waitcnt vmcnt(0)" ::: "memory");
    __builtin_amdgcn_sched_barrier(0);
    __builtin_amdgcn_s_barrier();
    __builtin_amdgcn_sched_barrier(0);
    cur ^= 1;
  }

  // ---- epilogue ----
  const int r0q = (lane >> 4) * 4;
  const int cc = lane & 15;
  const long crow0 = m0 + wr * 128;
  const long ccol0 = n0 + wc * 64;

  if (EPI == 1) {
#pragma unroll
    for (int m = 0; m < 8; ++m)
#pragma unroll
      for (int r = 0; r < 4; ++r) {
        long row = crow0 + m * 16 + r0q + r;
#pragma unroll
        for (int n = 0; n < 4; ++n)
          Cf32[row * N + ccol0 + n * 16 + cc] = acc[m][n][r];
      }
  } else if (EPI == 2) {
#pragma unroll
    for (int m = 0; m < 8; ++m)
#pragma unroll
      for (int r = 0; r < 4; ++r) {
        int srowi = (int)crow0 + m * 16 + r0q + r;
        int tok = sel[z * CAPP + srowi];
        float wgt = selw[z * CAPP + srowi];
        if (wgt != 0.0f) {
#pragma unroll
          for (int n = 0; n < 4; ++n)
            atomicAdd(&Cf32[(long)tok * N + ccol0 + n * 16 + cc],
                      acc[m][n][r] * wgt);
        }
      }
  } else {  // EPI == 3: SwiGLU fused store, output width N/2
    unsigned short* C = Cbf + (long)z * strideC;
    const int halfN = N >> 1;
    const long gcol0 = (ccol0 >> 1);  // n0/2 + wc*32
#pragma unroll
    for (int m = 0; m < 8; ++m)
#pragma unroll
      for (int r = 0; r < 4; ++r) {
        long row = crow0 + m * 16 + r0q + r;
#pragma unroll
        for (int q = 0; q < 2; ++q) {
          float x1v = acc[m][2 * q][r];
          float x2v = acc[m][2 * q + 1][r];
          float s = x2v / (1.0f + __expf(-x2v));
          C[row * halfN + gcol0 + q * 16 + cc] = f2bf(x1v * s);
        }
      }
  }
}

extern "C" void kernel_launch(void* const* d_in, const int* in_sizes, int n_in,
                              void* d_out, int out_size, void* d_ws,
                              size_t ws_size, hipStream_t stream) {
  (void)in_sizes; (void)n_in; (void)out_size; (void)ws_size;
  const float* x = (const float*)d_in[0];
  const float* gw = (const float*)d_in[1];
  const float* eb = (const float*)d_in[2];
  const float* sw1 = (const float*)d_in[3];
  const float* sw2 = (const float*)d_in[4];
  const float* rw1 = (const float*)d_in[5];
  const float* rw2 = (const float*)d_in[6];
  float* out = (float*)d_out;

  char* ws = (char*)d_ws;
  size_t off = 0;
  auto alloc = [&](size_t bytes) {
    size_t o = off;
    off += (bytes + 255) & ~(size_t)255;
    return o;
  };
  unsigned short* xb  = (unsigned short*)(ws + alloc((size_t)TOKS * DMODEL * 2));
  unsigned short* w1t = (unsigned short*)(ws + alloc((size_t)8 * DMODEL * (2 * FD) * 2));
  unsigned short* w2t = (unsigned short*)(ws + alloc((size_t)8 * DMODEL * FD * 2));
  unsigned short* a_sh = (unsigned short*)(ws + alloc((size_t)TOKS * FD * 2));
  unsigned short* a_r  = (unsigned short*)(ws + alloc((size_t)NEXP * CAPP * FD * 2));
  u64* keys = (u64*)(ws + alloc((size_t)NEXP * TOKS * 8));
  int* sel  = (int*)(ws + alloc((size_t)NEXP * CAPP * 4));
  float* selw = (float*)(ws + alloc((size_t)NEXP * CAPP * 4));

  const size_t LDSB = 131072;  // 2 x 64 KiB buffers

  // 1. x -> bf16
  k_convert_x<<<8192, 256, 0, stream>>>(x, xb, (long)TOKS * DMODEL / 4);
  // 2./3. weight transposes (w1 with x1/x2 16-block interleave for fused SwiGLU)
  dim3 tb(32, 8);
  k_transpose_bf16<true><<<dim3(64, 64, 8), tb, 0, stream>>>(sw1, rw1, w1t, DMODEL, 2 * FD);
  k_transpose_bf16<false><<<dim3(64, 32, 8), tb, 0, stream>>>(sw2, rw2, w2t, FD, DMODEL);
  // 4. gating
  k_gating<<<TOKS / 4, 256, 0, stream>>>(x, gw, eb, keys);
  // 5. per-expert selection (radix-select, no sort)
  k_select<<<NEXP, 1024, 0, stream>>>(keys, sel, selw);
  // 6. shared GEMM1 + fused SwiGLU: xb @ w1t[0]^T -> a_sh bf16 [8192,1024]
  k_gemm2ph<3, false><<<dim3(8, 32, 1), 512, LDSB, stream>>>(
      xb, w1t, a_sh, nullptr, nullptr, nullptr, 2 * FD, DMODEL, 0, 0, 0);
  // 7. shared GEMM2 -> d_out fp32 (full overwrite)
  k_gemm2ph<1, false><<<dim3(8, 32, 1), 512, LDSB, stream>>>(
      a_sh, w2t, nullptr, out, nullptr, nullptr, DMODEL, FD, 0, 0, 0);
  // 8. routed GEMM1 + fused SwiGLU (gathered A): -> a_r bf16 [7][1280][1024]
  k_gemm2ph<3, true><<<dim3(8, CAPP / 256, NEXP), 512, LDSB, stream>>>(
      xb, w1t + (size_t)DMODEL * (2 * FD), a_r, nullptr, sel, nullptr, 2 * FD,
      DMODEL, 0, (long)DMODEL * (2 * FD), (long)CAPP * FD);
  // 9. routed GEMM2 with weighted atomic scatter into d_out
  k_gemm2ph<2, false><<<dim3(8, CAPP / 256, NEXP), 512, LDSB, stream>>>(
      a_r, w2t + (size_t)DMODEL * FD, nullptr, out, sel, selw, DMODEL, FD,
      (long)CAPP * FD, (long)DMODEL * FD, 0);
}

// Round 6
// 518.276 us; speedup vs baseline: 1.3096x; 1.0249x over previous
//
#include <hip/hip_runtime.h>
#include <hip/hip_bf16.h>

typedef unsigned long long u64;
typedef __bf16 bf16x8 __attribute__((ext_vector_type(8)));
typedef float f32x4 __attribute__((ext_vector_type(4)));
typedef unsigned short ushort8_t __attribute__((ext_vector_type(8)));

#define TOKS 8192
#define DMODEL 2048
#define FD 1024
#define NEXP 7
#define CAP 1170
#define CAPP 1280

#define MFMA16(a, b, c) __builtin_amdgcn_mfma_f32_16x16x32_bf16(a, b, c, 0, 0, 0)

__device__ __forceinline__ unsigned short f2bf(float f) {
  __hip_bfloat16 b = __float2bfloat16(f);
  return __builtin_bit_cast(unsigned short, b);
}
__device__ __forceinline__ float bf2f(unsigned short u) {
  __hip_bfloat16 b = __builtin_bit_cast(__hip_bfloat16, u);
  return __bfloat162float(b);
}
__device__ __forceinline__ void gload_lds16(const void* g, void* l) {
  __builtin_amdgcn_global_load_lds(
      (const __attribute__((address_space(1))) void*)g,
      (__attribute__((address_space(3))) void*)l, 16, 0, 0);
}

// ---------------- x fp32 -> bf16 ----------------
__global__ void k_convert_x(const float* __restrict__ x,
                            unsigned short* __restrict__ xb, long n4) {
  long i = (long)blockIdx.x * blockDim.x + threadIdx.x;
  long stride = (long)gridDim.x * blockDim.x;
  for (; i < n4; i += stride) {
    float4 v = ((const float4*)x)[i];
    ushort4 o;
    o.x = f2bf(v.x); o.y = f2bf(v.y); o.z = f2bf(v.z); o.w = f2bf(v.w);
    ((ushort4*)xb)[i] = o;
  }
}

// ---------------- transpose fp32 [R][C] -> bf16 [C][R], batched z ----------------
// PERM: orig col c -> row ((c&1023)>>4)*32 + (c>>10)*16 + (c&15)  (x1/x2 16-block interleave)
template <bool PERM>
__global__ void k_transpose_bf16(const float* __restrict__ in0,
                                 const float* __restrict__ inr,
                                 unsigned short* __restrict__ out,
                                 int R, int C) {
  __shared__ float tile[32][33];
  int z = blockIdx.z;
  const float* in = (z == 0) ? in0 : (inr + (long)(z - 1) * R * C);
  unsigned short* o = out + (long)z * R * C;
  int c0 = blockIdx.x * 32;
  int r0 = blockIdx.y * 32;
  int tx = threadIdx.x, ty = threadIdx.y; // (32,8)
#pragma unroll
  for (int k = 0; k < 4; ++k)
    tile[ty + 8 * k][tx] = in[(long)(r0 + ty + 8 * k) * C + c0 + tx];
  __syncthreads();
#pragma unroll
  for (int k = 0; k < 4; ++k) {
    int c = c0 + ty + 8 * k;
    long orow = PERM ? (long)(((c & 1023) >> 4) * 32 + ((c >> 10) << 4) + (c & 15))
                     : (long)c;
    o[orow * R + r0 + tx] = f2bf(tile[tx][ty + 8 * k]);
  }
}

// ---------------- gating: fp64 dot, sigmoid, top-2, emit sort keys ----------------
__global__ void k_gating(const float* __restrict__ x,
                         const float* __restrict__ gw,   // [DMODEL][NEXP]
                         const float* __restrict__ bias, // [NEXP]
                         u64* __restrict__ keys) {       // [NEXP][TOKS]
  int wave = threadIdx.x >> 6;
  int lane = threadIdx.x & 63;
  int t = blockIdx.x * 4 + wave;
  const float* xr = x + (long)t * DMODEL;
  double acc[NEXP];
#pragma unroll
  for (int e = 0; e < NEXP; ++e) acc[e] = 0.0;
  for (int i = lane; i < DMODEL; i += 64) {
    double xv = (double)xr[i];
    const float* g = gw + (long)i * NEXP;
#pragma unroll
    for (int e = 0; e < NEXP; ++e) acc[e] += xv * (double)g[e];
  }
#pragma unroll
  for (int e = 0; e < NEXP; ++e) {
    for (int off = 32; off > 0; off >>= 1)
      acc[e] += __shfl_down(acc[e], off, 64);
  }
  if (lane == 0) {
    float aff[NEXP];
#pragma unroll
    for (int e = 0; e < NEXP; ++e) {
      double lg = acc[e] + (double)bias[e];
      aff[e] = (float)(1.0 / (1.0 + exp(-lg)));
    }
    int i1 = 0;
    for (int e = 1; e < NEXP; ++e) if (aff[e] > aff[i1]) i1 = e;
    int i2 = -1;
    for (int e = 0; e < NEXP; ++e) {
      if (e == i1) continue;
      if (i2 < 0 || aff[e] > aff[i2]) i2 = e;
    }
#pragma unroll
    for (int e = 0; e < NEXP; ++e) {
      u64 key = (u64)(0xFFFFFFFFu - (unsigned)t);
      if (e == i1 || e == i2) key |= ((u64)__float_as_uint(aff[e])) << 32;
      keys[(long)e * TOKS + t] = key;
    }
  }
}

// ---------------- per-expert radix-select of top-CAP keys + inverse map ----------------
// Keys distinct => CAP-th largest key T unique; selected == {key >= T}. Slot order
// arbitrary (output is a sum per token). inv[tok][<=2] records (e*CAPP+slot) for
// selected tokens with w>0, used by k_combine.
__global__ __launch_bounds__(1024) void k_select(
    const u64* __restrict__ keys, int* __restrict__ sel,
    float* __restrict__ selw, unsigned* __restrict__ cnt,
    int* __restrict__ inv) {
  __shared__ unsigned hist[256];
  __shared__ u64 s_prefix;
  __shared__ unsigned s_k;
  __shared__ unsigned s_cnt;
  const int e = blockIdx.x;
  const u64* kk = keys + (long)e * TOKS;
  const int tid = threadIdx.x;
  if (tid == 0) { s_prefix = 0; s_k = CAP; s_cnt = 0; }
  __syncthreads();
  for (int shift = 56; shift >= 0; shift -= 8) {
    if (tid < 256) hist[tid] = 0;
    __syncthreads();
    u64 pref = s_prefix;
    for (int i = tid; i < TOKS; i += 1024) {
      u64 key = kk[i];
      bool match = (shift == 56) || ((key >> (shift + 8)) == pref);
      if (match) atomicAdd(&hist[(unsigned)(key >> shift) & 255u], 1u);
    }
    __syncthreads();
    if (tid == 0) {
      unsigned k = s_k, cum = 0;
      for (int b = 255; b >= 0; --b) {
        unsigned c = hist[b];
        if (cum + c >= k) {
          s_prefix = (s_prefix << 8) | (unsigned)b;
          s_k = k - cum;
          break;
        }
        cum += c;
      }
    }
    __syncthreads();
  }
  const u64 T = s_prefix;  // exact CAP-th largest key
  for (int i = tid; i < TOKS; i += 1024) {
    u64 key = kk[i];
    if (key >= T) {
      unsigned p = atomicAdd(&s_cnt, 1u);
      int tok = (int)(0xFFFFFFFFu - (unsigned)(key & 0xFFFFFFFFull));
      unsigned vb = (unsigned)(key >> 32);
      sel[e * CAPP + p] = tok;
      selw[e * CAPP + p] = vb ? __uint_as_float(vb) : 0.0f;
      if (vb) {
        unsigned pos = atomicAdd(&cnt[tok], 1u);
        inv[tok * 2 + pos] = e * CAPP + (int)p;
      }
    }
  }
  for (int i = CAP + tid; i < CAPP; i += 1024) {
    sel[e * CAPP + i] = 0;
    selw[e * CAPP + i] = 0.0f;
  }
}

// ---------------- combine: out[tok] += sum over inv of routed rows (bf16) ----------------
__global__ __launch_bounds__(256) void k_combine(
    float* __restrict__ out, const unsigned short* __restrict__ rout,
    const int* __restrict__ inv, const unsigned* __restrict__ cnt) {
  const int tok = blockIdx.x;
  const unsigned c = cnt[tok];
  if (c == 0) return;
  int i0 = inv[tok * 2];
  int i1 = (c > 1) ? inv[tok * 2 + 1] : -1;
  if (c > 1 && i1 < i0) { int t = i0; i0 = i1; i1 = t; }  // canonical order
  const int col = threadIdx.x * 8;
  float* o = out + (long)tok * DMODEL + col;
  float4 v0 = *(float4*)o;
  float4 v1 = *(float4*)(o + 4);
  ushort8_t r0 = *(const ushort8_t*)&rout[(long)i0 * DMODEL + col];
#pragma unroll
  for (int j = 0; j < 4; ++j) { v0.x; }
  v0.x += bf2f(r0[0]); v0.y += bf2f(r0[1]); v0.z += bf2f(r0[2]); v0.w += bf2f(r0[3]);
  v1.x += bf2f(r0[4]); v1.y += bf2f(r0[5]); v1.z += bf2f(r0[6]); v1.w += bf2f(r0[7]);
  if (c > 1) {
    ushort8_t r1 = *(const ushort8_t*)&rout[(long)i1 * DMODEL + col];
    v0.x += bf2f(r1[0]); v0.y += bf2f(r1[1]); v0.z += bf2f(r1[2]); v0.w += bf2f(r1[3]);
    v1.x += bf2f(r1[4]); v1.y += bf2f(r1[5]); v1.z += bf2f(r1[6]); v1.w += bf2f(r1[7]);
  }
  *(float4*)o = v0;
  *(float4*)(o + 4) = v1;
}

// ---------------- 128x128 2-phase GEMM, BK=32, 32KiB LDS, 4 blocks/CU ----------------
// 256 thr = 4 waves (2M x 2N), per-wave 64x64 output. Double-buffered:
// STAGE(next) -> ds_read(cur) -> lgkmcnt(0) -> setprio MFMA -> vmcnt(0) -> barrier.
// Swizzle: 16B slot = kq ^ (r&3) ^ ((r>>2)&3), pre-swizzled global source, 2-way max.
// EPI: 1 -> fp32 store; 3 -> SwiGLU + bf16 store (N/2 cols); 4 -> weighted bf16 dense store.
template <int EPI, bool GATHER>
__global__ __launch_bounds__(256, 4) void k_gemm128(
    const unsigned short* __restrict__ Abase,
    const unsigned short* __restrict__ Bbase,
    unsigned short* __restrict__ Cbf, float* __restrict__ Cf32,
    const int* __restrict__ sel, const float* __restrict__ selw,
    int N, int K, long strideA, long strideB, long strideC) {
  __shared__ unsigned short lds[2][8192];  // per buf: A [0,4096) B [4096,8192) shorts
  const int tid = threadIdx.x;
  const int w = tid >> 6;
  const int lane = tid & 63;

  // T1: XCD-aware bijective swizzle (grid size multiple of 8)
  long lin = blockIdx.x + (long)gridDim.x * (blockIdx.y + (long)gridDim.y * blockIdx.z);
  long nwg = (long)gridDim.x * gridDim.y * gridDim.z;
  long swz = (lin & 7) * (nwg >> 3) + (lin >> 3);
  int bx = (int)(swz % gridDim.x);
  long rem = swz / gridDim.x;
  int by = (int)(rem % gridDim.y);
  int z = (int)(rem / gridDim.y);

  const long m0 = (long)by * 128;
  const long n0 = (long)bx * 128;
  const unsigned short* A = Abase + (GATHER ? 0L : (long)z * strideA);
  const unsigned short* Bm = Bbase + (long)z * strideB;

  const int wr = w >> 1;  // 0..1 M half
  const int wc = w & 1;   // 0..1 N half
  const int lr = lane & 15;
  const int kq = lane >> 4;

  // ---- staging: 4 chunks/thread (2 A + 2 B), pre-swizzled source col ----
  const int r_ = (w << 4) + (lane >> 2);        // base row 0..63; +c*64
  const int p_ = lane & 3;
  const unsigned short* aSrc[2];
  const unsigned short* bSrc[2];
#pragma unroll
  for (int c = 0; c < 2; ++c) {
    int r = c * 64 + r_;
    int q = p_ ^ ((r & 3) ^ ((r >> 2) & 3));
    long ar = GATHER ? (long)sel[z * CAPP + (int)m0 + r] : (m0 + r);
    aSrc[c] = A + ar * (long)K + q * 8;
    bSrc[c] = Bm + (n0 + r) * (long)K + q * 8;
  }
  const int dst0 = tid * 8;  // shorts; lane0 of wave w -> w*512 (wave-uniform base)

  auto STAGE = [&](int buf, int t) {
    const long ko = (long)t * 32;
#pragma unroll
    for (int c = 0; c < 2; ++c) {
      gload_lds16(aSrc[c] + ko, &lds[buf][c * 2048 + dst0]);
      gload_lds16(bSrc[c] + ko, &lds[buf][4096 + c * 2048 + dst0]);
    }
  };

  // ---- swizzled ds_read offsets ----
  const int gl = (lr & 3) ^ ((lr >> 2) & 3);
  const int slot = (kq ^ gl) * 8;
  const int aRow = wr * 64 + lr;  // + m*16
  const int bRow = wc * 64 + lr;  // + n*16

  const int nk = K >> 5;

  STAGE(0, 0);
  asm volatile("s_waitcnt vmcnt(0)" ::: "memory");
  __builtin_amdgcn_sched_barrier(0);
  __builtin_amdgcn_s_barrier();
  __builtin_amdgcn_sched_barrier(0);

  f32x4 acc[4][4] = {};
  int cur = 0;

#pragma unroll 1
  for (int t = 0; t < nk; ++t) {
    if (t + 1 < nk) STAGE(cur ^ 1, t + 1);
    const unsigned short* aSeg = &lds[cur][0];
    const unsigned short* bSeg = &lds[cur][4096];
    bf16x8 af[4], bf[4];
#pragma unroll
    for (int m = 0; m < 4; ++m)
      af[m] = *(const bf16x8*)&aSeg[(aRow + m * 16) * 32 + slot];
#pragma unroll
    for (int n = 0; n < 4; ++n)
      bf[n] = *(const bf16x8*)&bSeg[(bRow + n * 16) * 32 + slot];
    asm volatile("s_waitcnt lgkmcnt(0)" ::: "memory");
    __builtin_amdgcn_sched_barrier(0);
    __builtin_amdgcn_s_setprio(1);
#pragma unroll
    for (int m = 0; m < 4; ++m)
#pragma unroll
      for (int n = 0; n < 4; ++n)
        acc[m][n] = MFMA16(af[m], bf[n], acc[m][n]);
    __builtin_amdgcn_s_setprio(0);
    asm volatile("s_waitcnt vmcnt(0)" ::: "memory");
    __builtin_amdgcn_sched_barrier(0);
    __builtin_amdgcn_s_barrier();
    __builtin_amdgcn_sched_barrier(0);
    cur ^= 1;
  }

  // ---- epilogue ----
  const int r0q = (lane >> 4) * 4;
  const int cc = lane & 15;
  const long crow0 = m0 + wr * 64;
  const long ccol0 = n0 + wc * 64;

  if (EPI == 1) {
#pragma unroll
    for (int m = 0; m < 4; ++m)
#pragma unroll
      for (int r = 0; r < 4; ++r) {
        long row = crow0 + m * 16 + r0q + r;
#pragma unroll
        for (int n = 0; n < 4; ++n)
          Cf32[row * N + ccol0 + n * 16 + cc] = acc[m][n][r];
      }
  } else if (EPI == 3) {  // SwiGLU fused store, output width N/2
    unsigned short* C = Cbf + (long)z * strideC;
    const int halfN = N >> 1;
    const long gcol0 = (ccol0 >> 1);
#pragma unroll
    for (int m = 0; m < 4; ++m)
#pragma unroll
      for (int r = 0; r < 4; ++r) {
        long row = crow0 + m * 16 + r0q + r;
#pragma unroll
        for (int q = 0; q < 2; ++q) {
          float x1v = acc[m][2 * q][r];
          float x2v = acc[m][2 * q + 1][r];
          float s = x2v / (1.0f + __expf(-x2v));
          C[row * halfN + gcol0 + q * 16 + cc] = f2bf(x1v * s);
        }
      }
  } else {  // EPI == 4: weighted bf16 dense store (routed GEMM2)
#pragma unroll
    for (int m = 0; m < 4; ++m)
#pragma unroll
      for (int r = 0; r < 4; ++r) {
        int rloc = (int)crow0 + m * 16 + r0q + r;
        float wgt = selw[z * CAPP + rloc];
        unsigned short* C = Cbf + ((long)z * CAPP + rloc) * N;
#pragma unroll
        for (int n = 0; n < 4; ++n)
          C[ccol0 + n * 16 + cc] = f2bf(acc[m][n][r] * wgt);
      }
  }
}

extern "C" void kernel_launch(void* const* d_in, const int* in_sizes, int n_in,
                              void* d_out, int out_size, void* d_ws,
                              size_t ws_size, hipStream_t stream) {
  (void)in_sizes; (void)n_in; (void)out_size; (void)ws_size;
  const float* x = (const float*)d_in[0];
  const float* gw = (const float*)d_in[1];
  const float* eb = (const float*)d_in[2];
  const float* sw1 = (const float*)d_in[3];
  const float* sw2 = (const float*)d_in[4];
  const float* rw1 = (const float*)d_in[5];
  const float* rw2 = (const float*)d_in[6];
  float* out = (float*)d_out;

  char* ws = (char*)d_ws;
  size_t off = 0;
  auto alloc = [&](size_t bytes) {
    size_t o = off;
    off += (bytes + 255) & ~(size_t)255;
    return o;
  };
  unsigned short* xb  = (unsigned short*)(ws + alloc((size_t)TOKS * DMODEL * 2));
  unsigned short* w1t = (unsigned short*)(ws + alloc((size_t)8 * DMODEL * (2 * FD) * 2));
  unsigned short* w2t = (unsigned short*)(ws + alloc((size_t)8 * DMODEL * FD * 2));
  unsigned short* a_sh = (unsigned short*)(ws + alloc((size_t)TOKS * FD * 2));
  unsigned short* a_r  = (unsigned short*)(ws + alloc((size_t)NEXP * CAPP * FD * 2));
  unsigned short* r_out = (unsigned short*)(ws + alloc((size_t)NEXP * CAPP * DMODEL * 2));
  u64* keys = (u64*)(ws + alloc((size_t)NEXP * TOKS * 8));
  int* sel  = (int*)(ws + alloc((size_t)NEXP * CAPP * 4));
  float* selw = (float*)(ws + alloc((size_t)NEXP * CAPP * 4));
  unsigned* cnt = (unsigned*)(ws + alloc((size_t)TOKS * 4));
  int* inv = (int*)(ws + alloc((size_t)TOKS * 2 * 4));

  // 1. x -> bf16
  k_convert_x<<<8192, 256, 0, stream>>>(x, xb, (long)TOKS * DMODEL / 4);
  // 2./3. weight transposes (w1 with x1/x2 16-block interleave for fused SwiGLU)
  dim3 tb(32, 8);
  k_transpose_bf16<true><<<dim3(64, 64, 8), tb, 0, stream>>>(sw1, rw1, w1t, DMODEL, 2 * FD);
  k_transpose_bf16<false><<<dim3(64, 32, 8), tb, 0, stream>>>(sw2, rw2, w2t, FD, DMODEL);
  // 4. gating
  k_gating<<<TOKS / 4, 256, 0, stream>>>(x, gw, eb, keys);
  // 5. per-expert selection (radix-select) + inverse map
  hipMemsetAsync(cnt, 0, (size_t)TOKS * 4, stream);
  k_select<<<NEXP, 1024, 0, stream>>>(keys, sel, selw, cnt, inv);
  // 6. shared GEMM1 + fused SwiGLU: xb @ w1t[0]^T -> a_sh bf16 [8192,1024]
  k_gemm128<3, false><<<dim3(16, 64, 1), 256, 0, stream>>>(
      xb, w1t, a_sh, nullptr, nullptr, nullptr, 2 * FD, DMODEL, 0, 0, 0);
  // 7. shared GEMM2 -> out fp32 (full overwrite)
  k_gemm128<1, false><<<dim3(16, 64, 1), 256, 0, stream>>>(
      a_sh, w2t, nullptr, out, nullptr, nullptr, DMODEL, FD, 0, 0, 0);
  // 8. routed GEMM1 + fused SwiGLU (gathered A) -> a_r bf16 [7*1280,1024]
  k_gemm128<3, true><<<dim3(16, CAPP / 128, NEXP), 256, 0, stream>>>(
      xb, w1t + (size_t)DMODEL * (2 * FD), a_r, nullptr, sel, nullptr, 2 * FD,
      DMODEL, 0, (long)DMODEL * (2 * FD), (long)CAPP * FD);
  // 9. routed GEMM2 -> weighted bf16 dense r_out [7*1280,2048]
  k_gemm128<4, false><<<dim3(16, CAPP / 128, NEXP), 256, 0, stream>>>(
      a_r, w2t + (size_t)DMODEL * FD, r_out, nullptr, sel, selw, DMODEL, FD,
      (long)CAPP * FD, (long)DMODEL * FD, 0);
  // 10. combine: out[tok] += sum of routed rows
  k_combine<<<TOKS, 256, 0, stream>>>(out, r_out, inv, cnt);
}

// Round 7
// 495.768 us; speedup vs baseline: 1.3691x; 1.0454x over previous
//
#include <hip/hip_runtime.h>
#include <hip/hip_bf16.h>

typedef unsigned long long u64;
typedef __bf16 bf16x8 __attribute__((ext_vector_type(8)));
typedef float f32x4 __attribute__((ext_vector_type(4)));
typedef unsigned short ushort8_t __attribute__((ext_vector_type(8)));

#define TOKS 8192
#define DMODEL 2048
#define FD 1024
#define NEXP 7
#define CAP 1170
#define CAPP 1280
#define URT 134  // unified row tiles: 64 shared + 7*10 routed

#define MFMA16(a, b, c) __builtin_amdgcn_mfma_f32_16x16x32_bf16(a, b, c, 0, 0, 0)

__device__ __forceinline__ unsigned short f2bf(float f) {
  __hip_bfloat16 b = __float2bfloat16(f);
  return __builtin_bit_cast(unsigned short, b);
}
__device__ __forceinline__ float bf2f(unsigned short u) {
  __hip_bfloat16 b = __builtin_bit_cast(__hip_bfloat16, u);
  return __bfloat162float(b);
}
__device__ __forceinline__ void gload_lds16(const void* g, void* l) {
  __builtin_amdgcn_global_load_lds(
      (const __attribute__((address_space(1))) void*)g,
      (__attribute__((address_space(3))) void*)l, 16, 0, 0);
}

// ---------------- fused x fp32->bf16 convert + gating (1 block = 1 token) ----------------
__global__ __launch_bounds__(256) void k_conv_gate(
    const float* __restrict__ x, const float* __restrict__ gw,
    const float* __restrict__ bias, unsigned short* __restrict__ xb,
    u64* __restrict__ keys) {
  const int t = blockIdx.x;
  const int tid = threadIdx.x;
  const int lane = tid & 63, wv = tid >> 6;
  const float* xr = x + (long)t * DMODEL;
  const int i0 = tid * 8;
  float4 v0 = *(const float4*)&xr[i0];
  float4 v1 = *(const float4*)&xr[i0 + 4];
  float xv[8] = {v0.x, v0.y, v0.z, v0.w, v1.x, v1.y, v1.z, v1.w};
  ushort8_t o;
#pragma unroll
  for (int j = 0; j < 8; ++j) o[j] = f2bf(xv[j]);
  *(ushort8_t*)&xb[(long)t * DMODEL + i0] = o;
  double acc[NEXP];
#pragma unroll
  for (int e = 0; e < NEXP; ++e) acc[e] = 0.0;
#pragma unroll
  for (int j = 0; j < 8; ++j) {
    const float* g = gw + (long)(i0 + j) * NEXP;
    double xd = (double)xv[j];
#pragma unroll
    for (int e = 0; e < NEXP; ++e) acc[e] += xd * (double)g[e];
  }
#pragma unroll
  for (int e = 0; e < NEXP; ++e)
    for (int off = 32; off > 0; off >>= 1)
      acc[e] += __shfl_down(acc[e], off, 64);
  __shared__ double red[4][NEXP];
  if (lane == 0)
#pragma unroll
    for (int e = 0; e < NEXP; ++e) red[wv][e] = acc[e];
  __syncthreads();
  if (tid == 0) {
    float aff[NEXP];
#pragma unroll
    for (int e = 0; e < NEXP; ++e) {
      double lg = red[0][e] + red[1][e] + red[2][e] + red[3][e] + (double)bias[e];
      aff[e] = (float)(1.0 / (1.0 + exp(-lg)));
    }
    int i1 = 0;
    for (int e = 1; e < NEXP; ++e) if (aff[e] > aff[i1]) i1 = e;
    int i2 = -1;
    for (int e = 0; e < NEXP; ++e) {
      if (e == i1) continue;
      if (i2 < 0 || aff[e] > aff[i2]) i2 = e;
    }
#pragma unroll
    for (int e = 0; e < NEXP; ++e) {
      u64 key = (u64)(0xFFFFFFFFu - (unsigned)t);
      if (e == i1 || e == i2) key |= ((u64)__float_as_uint(aff[e])) << 32;
      keys[(long)e * TOKS + t] = key;
    }
  }
}

// ---------------- transpose fp32 [R][C] -> bf16 [C][R], batched z ----------------
// PERM: orig col c -> row ((c&1023)>>4)*32 + (c>>10)*16 + (c&15)  (x1/x2 16-block interleave)
template <bool PERM>
__global__ void k_transpose_bf16(const float* __restrict__ in0,
                                 const float* __restrict__ inr,
                                 unsigned short* __restrict__ out,
                                 int R, int C) {
  __shared__ float tile[32][33];
  int z = blockIdx.z;
  const float* in = (z == 0) ? in0 : (inr + (long)(z - 1) * R * C);
  unsigned short* o = out + (long)z * R * C;
  int c0 = blockIdx.x * 32;
  int r0 = blockIdx.y * 32;
  int tx = threadIdx.x, ty = threadIdx.y; // (32,8)
#pragma unroll
  for (int k = 0; k < 4; ++k)
    tile[ty + 8 * k][tx] = in[(long)(r0 + ty + 8 * k) * C + c0 + tx];
  __syncthreads();
#pragma unroll
  for (int k = 0; k < 4; ++k) {
    int c = c0 + ty + 8 * k;
    long orow = PERM ? (long)(((c & 1023) >> 4) * 32 + ((c >> 10) << 4) + (c & 15))
                     : (long)c;
    o[orow * R + r0 + tx] = f2bf(tile[tx][ty + 8 * k]);
  }
}

// ---------------- per-expert radix-select of top-CAP keys + inverse map ----------------
__global__ __launch_bounds__(1024) void k_select(
    const u64* __restrict__ keys, int* __restrict__ sel,
    float* __restrict__ selw, unsigned* __restrict__ cnt,
    int* __restrict__ inv) {
  __shared__ unsigned hist[256];
  __shared__ u64 s_prefix;
  __shared__ unsigned s_k;
  __shared__ unsigned s_cnt;
  const int e = blockIdx.x;
  const u64* kk = keys + (long)e * TOKS;
  const int tid = threadIdx.x;
  if (tid == 0) { s_prefix = 0; s_k = CAP; s_cnt = 0; }
  __syncthreads();
  for (int shift = 56; shift >= 0; shift -= 8) {
    if (tid < 256) hist[tid] = 0;
    __syncthreads();
    u64 pref = s_prefix;
    for (int i = tid; i < TOKS; i += 1024) {
      u64 key = kk[i];
      bool match = (shift == 56) || ((key >> (shift + 8)) == pref);
      if (match) atomicAdd(&hist[(unsigned)(key >> shift) & 255u], 1u);
    }
    __syncthreads();
    if (tid == 0) {
      unsigned k = s_k, cum = 0;
      for (int b = 255; b >= 0; --b) {
        unsigned c = hist[b];
        if (cum + c >= k) {
          s_prefix = (s_prefix << 8) | (unsigned)b;
          s_k = k - cum;
          break;
        }
        cum += c;
      }
    }
    __syncthreads();
  }
  const u64 T = s_prefix;  // exact CAP-th largest key
  for (int i = tid; i < TOKS; i += 1024) {
    u64 key = kk[i];
    if (key >= T) {
      unsigned p = atomicAdd(&s_cnt, 1u);
      int tok = (int)(0xFFFFFFFFu - (unsigned)(key & 0xFFFFFFFFull));
      unsigned vb = (unsigned)(key >> 32);
      sel[e * CAPP + p] = tok;
      selw[e * CAPP + p] = vb ? __uint_as_float(vb) : 0.0f;
      if (vb) {
        unsigned pos = atomicAdd(&cnt[tok], 1u);
        inv[tok * 2 + pos] = e * CAPP + (int)p;
      }
    }
  }
  for (int i = CAP + tid; i < CAPP; i += 1024) {
    sel[e * CAPP + i] = 0;
    selw[e * CAPP + i] = 0.0f;
  }
}

// ---------------- combine: out[tok] += sum over inv of routed rows (bf16) ----------------
__global__ __launch_bounds__(256) void k_combine(
    float* __restrict__ out, const unsigned short* __restrict__ rout,
    const int* __restrict__ inv, const unsigned* __restrict__ cnt) {
  const int tok = blockIdx.x;
  const unsigned c = cnt[tok];
  if (c == 0) return;
  int i0 = inv[tok * 2];
  int i1 = (c > 1) ? inv[tok * 2 + 1] : -1;
  if (c > 1 && i1 < i0) { int t = i0; i0 = i1; i1 = t; }  // canonical order
  const int col = threadIdx.x * 8;
  float* o = out + (long)tok * DMODEL + col;
  float4 v0 = *(float4*)o;
  float4 v1 = *(float4*)(o + 4);
  ushort8_t r0 = *(const ushort8_t*)&rout[(long)i0 * DMODEL + col];
  v0.x += bf2f(r0[0]); v0.y += bf2f(r0[1]); v0.z += bf2f(r0[2]); v0.w += bf2f(r0[3]);
  v1.x += bf2f(r0[4]); v1.y += bf2f(r0[5]); v1.z += bf2f(r0[6]); v1.w += bf2f(r0[7]);
  if (c > 1) {
    ushort8_t r1 = *(const ushort8_t*)&rout[(long)i1 * DMODEL + col];
    v0.x += bf2f(r1[0]); v0.y += bf2f(r1[1]); v0.z += bf2f(r1[2]); v0.w += bf2f(r1[3]);
    v1.x += bf2f(r1[4]); v1.y += bf2f(r1[5]); v1.z += bf2f(r1[6]); v1.w += bf2f(r1[7]);
  }
  *(float4*)o = v0;
  *(float4*)(o + 4) = v1;
}

// ---------------- fused 128x128 2-phase GEMM over unified (shared+routed) rows ----------------
// WHICH=1: xb[gathered] @ w1t[zw]^T -> SwiGLU -> a_all (rows: [0,8192) shared, then 7*1280 routed)
// WHICH=2: a_all @ w2t[zw]^T -> z=0: fp32 out; z>0: weighted bf16 r_out
// Grid (16, 134). Locality swizzle: per-XCD contiguous 268-tile run over global
// supertiles of (8 rows x 16 cols), col-outer/row-inner inside -> B col-tile reused
// 8x from L2, A supertile (4MB) L2-resident.
template <int WHICH>
__global__ __launch_bounds__(256, 4) void k_ffn(
    const unsigned short* __restrict__ Abase,
    const unsigned short* __restrict__ Wbase,
    unsigned short* __restrict__ a_all, float* __restrict__ out,
    unsigned short* __restrict__ r_out,
    const int* __restrict__ sel, const float* __restrict__ selw) {
  constexpr int K = (WHICH == 1) ? DMODEL : FD;
  constexpr int N = (WHICH == 1) ? 2 * FD : DMODEL;
  constexpr int nk = K >> 5;
  __shared__ unsigned short lds[2][8192];
  const int tid = threadIdx.x;
  const int w = tid >> 6;
  const int lane = tid & 63;

  // ---- locality swizzle ----
  int lin = blockIdx.x + ((int)blockIdx.y << 4);
  int gt = (lin & 7) * 268 + (lin >> 3);  // nwg = 2144 = 8*268
  int ct, rt;
  int su;
  if (gt < 2048) { su = gt >> 7; int rr = gt & 127; ct = rr >> 3; rt = rr & 7; }
  else           { su = 16;      int rr = gt - 2048; ct = rr / 6; rt = rr % 6; }
  const int by_u = su * 8 + rt;  // 0..133
  const int bx = ct;             // 0..15

  int e, zw, m0l;
  if (by_u < 64) { e = -1; zw = 0; m0l = by_u << 7; }
  else { int q = by_u - 64; e = q / 10; zw = e + 1; m0l = (q % 10) << 7; }
  const long crow0_u = (e < 0) ? (long)m0l : (8192 + (long)e * CAPP + m0l);
  const long n0 = (long)bx * 128;
  const unsigned short* Bm = Wbase + (long)zw * N * K;

  // ---- staging source pointers (pre-swizzled col; involution f(r) = (r>>1)&3) ----
  const int r_ = (w << 4) + (lane >> 2);  // 0..63, +c*64
  const int p_ = lane & 3;
  const unsigned short* aSrc[2];
  const unsigned short* bSrc[2];
#pragma unroll
  for (int c = 0; c < 2; ++c) {
    int rsg = c * 64 + r_;
    int q = p_ ^ ((rsg >> 1) & 3);
    long arow;
    if (WHICH == 1)
      arow = (e < 0) ? (long)(m0l + rsg) : (long)sel[e * CAPP + m0l + rsg];
    else
      arow = crow0_u + rsg;
    aSrc[c] = Abase + arow * (long)K + q * 8;
    bSrc[c] = Bm + (n0 + rsg) * (long)K + q * 8;
  }
  const int dst0 = tid * 8;

  auto STAGE = [&](int buf, int kt) {
    const long ko = (long)kt * 32;
#pragma unroll
    for (int c = 0; c < 2; ++c) {
      gload_lds16(aSrc[c] + ko, &lds[buf][c * 2048 + dst0]);
      gload_lds16(bSrc[c] + ko, &lds[buf][4096 + c * 2048 + dst0]);
    }
  };

  const int wr = w >> 1, wc = w & 1;
  const int lr = lane & 15, kq = lane >> 4;
  const int slot = (kq ^ ((lr >> 1) & 3)) * 8;  // proven zero-conflict involution
  const int aRow = wr * 64 + lr;
  const int bRow = wc * 64 + lr;

  STAGE(0, 0);
  asm volatile("s_waitcnt vmcnt(0)" ::: "memory");
  __builtin_amdgcn_sched_barrier(0);
  __builtin_amdgcn_s_barrier();
  __builtin_amdgcn_sched_barrier(0);

  f32x4 acc[4][4] = {};
  int cur = 0;

#pragma unroll 1
  for (int kt = 0; kt < nk; ++kt) {
    if (kt + 1 < nk) STAGE(cur ^ 1, kt + 1);
    const unsigned short* aSeg = &lds[cur][0];
    const unsigned short* bSeg = &lds[cur][4096];
    bf16x8 af[4], bf[4];
#pragma unroll
    for (int m = 0; m < 4; ++m)
      af[m] = *(const bf16x8*)&aSeg[(aRow + m * 16) * 32 + slot];
#pragma unroll
    for (int n = 0; n < 4; ++n)
      bf[n] = *(const bf16x8*)&bSeg[(bRow + n * 16) * 32 + slot];
    asm volatile("s_waitcnt lgkmcnt(0)" ::: "memory");
    __builtin_amdgcn_sched_barrier(0);
    __builtin_amdgcn_s_setprio(1);
#pragma unroll
    for (int m = 0; m < 4; ++m)
#pragma unroll
      for (int n = 0; n < 4; ++n)
        acc[m][n] = MFMA16(af[m], bf[n], acc[m][n]);
    __builtin_amdgcn_s_setprio(0);
    asm volatile("s_waitcnt vmcnt(0)" ::: "memory");
    __builtin_amdgcn_sched_barrier(0);
    __builtin_amdgcn_s_barrier();
    __builtin_amdgcn_sched_barrier(0);
    cur ^= 1;
  }

  // ---- epilogue ----
  const int r0q = (lane >> 4) * 4;
  const int cc = lane & 15;

  if (WHICH == 1) {  // SwiGLU fused store into a_all [., FD]
    const long gcol0 = (n0 >> 1) + wc * 32;
#pragma unroll
    for (int m = 0; m < 4; ++m)
#pragma unroll
      for (int rj = 0; rj < 4; ++rj) {
        long row = crow0_u + wr * 64 + m * 16 + r0q + rj;
#pragma unroll
        for (int q2 = 0; q2 < 2; ++q2) {
          float x1v = acc[m][2 * q2][rj];
          float x2v = acc[m][2 * q2 + 1][rj];
          float s = x2v / (1.0f + __expf(-x2v));
          a_all[row * FD + gcol0 + q2 * 16 + cc] = f2bf(x1v * s);
        }
      }
  } else {
    const long ccol0 = n0 + wc * 64;
    if (e < 0) {  // shared -> fp32 out (full overwrite)
#pragma unroll
      for (int m = 0; m < 4; ++m)
#pragma unroll
        for (int rj = 0; rj < 4; ++rj) {
          long row = m0l + wr * 64 + m * 16 + r0q + rj;
#pragma unroll
          for (int n = 0; n < 4; ++n)
            out[row * DMODEL + ccol0 + n * 16 + cc] = acc[m][n][rj];
        }
    } else {  // routed -> weighted bf16 dense r_out
#pragma unroll
      for (int m = 0; m < 4; ++m)
#pragma unroll
        for (int rj = 0; rj < 4; ++rj) {
          int lrow = m0l + wr * 64 + m * 16 + r0q + rj;
          float wgt = selw[e * CAPP + lrow];
          unsigned short* C = r_out + ((long)e * CAPP + lrow) * DMODEL;
#pragma unroll
          for (int n = 0; n < 4; ++n)
            C[ccol0 + n * 16 + cc] = f2bf(acc[m][n][rj] * wgt);
        }
    }
  }
}

extern "C" void kernel_launch(void* const* d_in, const int* in_sizes, int n_in,
                              void* d_out, int out_size, void* d_ws,
                              size_t ws_size, hipStream_t stream) {
  (void)in_sizes; (void)n_in; (void)out_size; (void)ws_size;
  const float* x = (const float*)d_in[0];
  const float* gw = (const float*)d_in[1];
  const float* eb = (const float*)d_in[2];
  const float* sw1 = (const float*)d_in[3];
  const float* sw2 = (const float*)d_in[4];
  const float* rw1 = (const float*)d_in[5];
  const float* rw2 = (const float*)d_in[6];
  float* out = (float*)d_out;

  char* ws = (char*)d_ws;
  size_t off = 0;
  auto alloc = [&](size_t bytes) {
    size_t o = off;
    off += (bytes + 255) & ~(size_t)255;
    return o;
  };
  unsigned short* xb    = (unsigned short*)(ws + alloc((size_t)TOKS * DMODEL * 2));
  unsigned short* w1t   = (unsigned short*)(ws + alloc((size_t)8 * DMODEL * (2 * FD) * 2));
  unsigned short* w2t   = (unsigned short*)(ws + alloc((size_t)8 * DMODEL * FD * 2));
  unsigned short* a_all = (unsigned short*)(ws + alloc((size_t)(TOKS + NEXP * CAPP) * FD * 2));
  unsigned short* r_out = (unsigned short*)(ws + alloc((size_t)NEXP * CAPP * DMODEL * 2));
  u64* keys = (u64*)(ws + alloc((size_t)NEXP * TOKS * 8));
  int* sel  = (int*)(ws + alloc((size_t)NEXP * CAPP * 4));
  float* selw = (float*)(ws + alloc((size_t)NEXP * CAPP * 4));
  unsigned* cnt = (unsigned*)(ws + alloc((size_t)TOKS * 4));
  int* inv = (int*)(ws + alloc((size_t)TOKS * 2 * 4));

  // 1. fused convert + gating (single read of x)
  k_conv_gate<<<TOKS, 256, 0, stream>>>(x, gw, eb, xb, keys);
  // 2./3. weight transposes (w1 with x1/x2 16-block interleave for fused SwiGLU)
  dim3 tb(32, 8);
  k_transpose_bf16<true><<<dim3(64, 64, 8), tb, 0, stream>>>(sw1, rw1, w1t, DMODEL, 2 * FD);
  k_transpose_bf16<false><<<dim3(64, 32, 8), tb, 0, stream>>>(sw2, rw2, w2t, FD, DMODEL);
  // 4. per-expert selection (radix-select) + inverse map
  hipMemsetAsync(cnt, 0, (size_t)TOKS * 4, stream);
  k_select<<<NEXP, 1024, 0, stream>>>(keys, sel, selw, cnt, inv);
  // 5. fused GEMM1 (shared + all routed experts) + SwiGLU -> a_all
  k_ffn<1><<<dim3(16, URT), 256, 0, stream>>>(xb, w1t, a_all, nullptr, nullptr,
                                              sel, nullptr);
  // 6. fused GEMM2 -> out (shared, fp32) / r_out (routed, weighted bf16)
  k_ffn<2><<<dim3(16, URT), 256, 0, stream>>>(a_all, w2t, nullptr, out, r_out,
                                              nullptr, selw);
  // 7. combine: out[tok] += sum of routed rows
  k_combine<<<TOKS, 256, 0, stream>>>(out, r_out, inv, cnt);
}